// Round 12
// baseline (205.658 us; speedup 1.0000x reference)
//
#include <hip/hip_runtime.h>
#include <math.h>

// Problem constants
#define NRES 512
#define CSZ  384
#define CZ   128
#define CC   16
#define PQ   4
#define PV   8
#define NH   12

#define HC    (NH*CC)        // 192
#define HPQ3  (NH*PQ*3)      // 144
#define HPV3  (NH*PV*3)      // 288
#define ATTD  (NH*(CZ+CC+PV*4)) // 2112

// workspace layout (floats)
#define OFF_Q   0
#define OFF_K   (OFF_Q  + NRES*HC)     // 98304
#define OFF_V   (OFF_K  + NRES*HC)     // 196608
#define OFF_LQ  (OFF_V  + NRES*HC)     // 294912
#define OFF_LK  (OFF_LQ + NRES*HPQ3)   // 368640
#define OFF_LVP (OFF_LK + NRES*HPQ3)   // 442368
#define OFF_ATT (OFF_LVP+ NRES*HPV3)   // 589824  (512*2112 = 1081344 floats)
#define OFF_LOG (OFF_ATT + NRES*ATTD)  // 1671168: qk-logits [512][12][512]
// partials for the output GEMM reuse the logits region (dead by then)
#define OFF_PART OFF_LOG
#define LOG_FLOATS (NRES*NH*NRES)      // 3145728

// khat/qhat scratch lives in the (not yet written) ATT region:
#define OFF_KH  OFF_ATT
#define OFF_QH  (OFF_ATT + NH*NRES*32)   // +196608

#define SCALE_SINGLE 0.25f
#define SCALE_FRAME  (-0.1178511301977579f)  // -1/sqrt(72)

#define LROW 516   // padded logit row
#define ZP   516   // transposed pair-stage stride (2-way bank alias = free)

// ---------------------------------------------------------------------------
// Kernel 1: projection GEMM  C[512,1152] = S[512,384] @ Wcat[384,1152]
// ---------------------------------------------------------------------------
#define PJ_BM 32
#define PJ_BN 64
#define PJ_BK 32
#define PJ_NK (CSZ/PJ_BK)   // 12
#define PJ_AP 388           // padded A row (floats), mult of 4

__global__ __launch_bounds__(256) void k_proj2(
    const float* __restrict__ S,
    const float* __restrict__ Wq, const float* __restrict__ Wk,
    const float* __restrict__ Wv, const float* __restrict__ Wqp,
    const float* __restrict__ Wkp, const float* __restrict__ Wvp,
    float* __restrict__ ws)
{
  __shared__ __align__(16) float A_s[PJ_BM][PJ_AP];   // 49664 B
  __shared__ __align__(16) float B_s[PJ_BK][PJ_BN];   //  8192 B

  const int t  = threadIdx.x;
  const int rb = blockIdx.x / 18;          // 0..15 row tile
  const int cb = blockIdx.x % 18;          // 0..17 col tile
  const int tc = t & 15, tr = t >> 4;      // micro-tile coords

  #pragma unroll
  for (int j = 0; j < 12; ++j) {
    int idx = t + j*256;
    int row = idx / 96, kq = idx % 96;
    float4 v4 = *(const float4*)(S + (size_t)(rb*PJ_BM + row)*CSZ + kq*4);
    *(float4*)&A_s[row][kq*4] = v4;
  }

  const float* Wp[2]; int ncB[2], lcB[2], kkB[2], cqB[2];
  #pragma unroll
  for (int j = 0; j < 2; ++j) {
    int idx = t + j*256;
    int kk = idx >> 4, cq = idx & 15;
    kkB[j] = kk; cqB[j] = cq;
    int col = cb*PJ_BN + cq*4;
    if      (col < 192) { Wp[j]=Wq;  ncB[j]=192; lcB[j]=col;     }
    else if (col < 384) { Wp[j]=Wk;  ncB[j]=192; lcB[j]=col-192; }
    else if (col < 576) { Wp[j]=Wv;  ncB[j]=192; lcB[j]=col-384; }
    else if (col < 720) { Wp[j]=Wqp; ncB[j]=144; lcB[j]=col-576; }
    else if (col < 864) { Wp[j]=Wkp; ncB[j]=144; lcB[j]=col-720; }
    else                { Wp[j]=Wvp; ncB[j]=288; lcB[j]=col-864; }
  }

  float4 bw[2];
  #pragma unroll
  for (int j = 0; j < 2; ++j)
    bw[j] = *(const float4*)(Wp[j] + (size_t)kkB[j]*ncB[j] + lcB[j]);

  float acc[2][4];
  #pragma unroll
  for (int i=0;i<2;i++)
    #pragma unroll
    for (int jj=0;jj<4;jj++) acc[i][jj]=0.f;

  for (int ki = 0; ki < PJ_NK; ++ki) {
    __syncthreads();
    #pragma unroll
    for (int j = 0; j < 2; ++j)
      *(float4*)&B_s[kkB[j]][cqB[j]*4] = bw[j];
    __syncthreads();

    if (ki + 1 < PJ_NK) {
      #pragma unroll
      for (int j = 0; j < 2; ++j)
        bw[j] = *(const float4*)(Wp[j] + (size_t)((ki+1)*PJ_BK + kkB[j])*ncB[j] + lcB[j]);
    }

    #pragma unroll
    for (int kk4 = 0; kk4 < PJ_BK/4; ++kk4) {
      float4 a0 = *(const float4*)&A_s[tr*2+0][ki*PJ_BK + kk4*4];
      float4 a1 = *(const float4*)&A_s[tr*2+1][ki*PJ_BK + kk4*4];
      const float* a0p = (const float*)&a0;
      const float* a1p = (const float*)&a1;
      #pragma unroll
      for (int e = 0; e < 4; ++e) {
        float4 b4 = *(const float4*)&B_s[kk4*4+e][tc*4];
        float f0 = a0p[e], f1 = a1p[e];
        acc[0][0] += f0*b4.x; acc[0][1] += f0*b4.y; acc[0][2] += f0*b4.z; acc[0][3] += f0*b4.w;
        acc[1][0] += f1*b4.x; acc[1][1] += f1*b4.y; acc[1][2] += f1*b4.z; acc[1][3] += f1*b4.w;
      }
    }
  }

  {
    int col = cb*PJ_BN + tc*4;
    float* dst; int stride; int lcc;
    if      (col < 192) { dst = ws+OFF_Q;   stride=192; lcc=col;     }
    else if (col < 384) { dst = ws+OFF_K;   stride=192; lcc=col-192; }
    else if (col < 576) { dst = ws+OFF_V;   stride=192; lcc=col-384; }
    else if (col < 720) { dst = ws+OFF_LQ;  stride=144; lcc=col-576; }
    else if (col < 864) { dst = ws+OFF_LK;  stride=144; lcc=col-720; }
    else                { dst = ws+OFF_LVP; stride=288; lcc=col-864; }
    #pragma unroll
    for (int i = 0; i < 2; ++i) {
      int row = rb*PJ_BM + tr*2 + i;
      *(float4*)&dst[(size_t)row*stride + lcc] =
          make_float4(acc[i][0], acc[i][1], acc[i][2], acc[i][3]);
    }
  }
}

// ---------------------------------------------------------------------------
// Kernel 1b: apply rigid frames in place to qp, kp, vp -> lq, lk, lvp
// ---------------------------------------------------------------------------
__global__ __launch_bounds__(256) void k_frames(
    const float* __restrict__ rot, const float* __restrict__ trans,
    float* __restrict__ ws)
{
  int gid = blockIdx.x*256 + threadIdx.x;
  if (gid >= NRES*192) return;
  int m = gid / 192;
  int rest = gid % 192;
  float* base; int pidx;
  if      (rest <  48) { base = ws + OFF_LQ  + (size_t)m*HPQ3; pidx = rest;     }
  else if (rest <  96) { base = ws + OFF_LK  + (size_t)m*HPQ3; pidx = rest-48;  }
  else                 { base = ws + OFF_LVP + (size_t)m*HPV3; pidx = rest-96;  }
  float x = base[pidx*3+0], y = base[pidx*3+1], z = base[pidx*3+2];
  const float* R = rot + (size_t)m*9;
  const float* T = trans + (size_t)m*3;
  float o0 = R[0]*x + R[1]*y + R[2]*z + T[0];
  float o1 = R[3]*x + R[4]*y + R[5]*z + T[1];
  float o2 = R[6]*x + R[7]*y + R[8]*z + T[2];
  base[pidx*3+0]=o0; base[pidx*3+1]=o1; base[pidx*3+2]=o2;
}

// ---------------------------------------------------------------------------
// Kernel 1c: build khat[h][m][32] and qhat[h][n][32] (correctness-proven).
// ---------------------------------------------------------------------------
__global__ __launch_bounds__(256) void k_hat(
    const float* __restrict__ scale_head, float* __restrict__ ws)
{
  const int r = blockIdx.x;
  const int t = threadIdx.x;
  __shared__ float sSp[NH];
  if (t < NH) { float x = scale_head[t];
                sSp[t] = (x > 20.f) ? x : log1pf(__expf(x)); }
  __syncthreads();

  for (int i = t; i < NH*32; i += 256) {
    const int h = i >> 5, j = i & 31;
    const float* kk = ws + OFF_K  + (size_t)r*HC   + h*CC;
    const float* lk = ws + OFF_LK + (size_t)r*HPQ3 + h*12;
    const float* qq = ws + OFF_Q  + (size_t)r*HC   + h*CC;
    const float* lq = ws + OFF_LQ + (size_t)r*HPQ3 + h*12;
    float kv, qv;
    if (j < 16)      { kv = kk[j];    qv = SCALE_SINGLE * qq[j]; }
    else if (j < 28) { kv = lk[j-16]; qv = -2.f*SCALE_FRAME*sSp[h]*lq[j-16]; }
    else if (j == 28) {
      float s2 = 0.f;
      #pragma unroll
      for (int e=0;e<12;e++) { float v = lk[e]; s2 += v*v; }
      kv = SCALE_FRAME * sSp[h] * s2;
      qv = 1.f;
    } else { kv = 0.f; qv = 0.f; }
    ws[OFF_KH + ((size_t)h*NRES + r)*32 + j] = kv;
    ws[OFF_QH + ((size_t)h*NRES + r)*32 + j] = qv;
  }
}

// ---------------------------------------------------------------------------
// Kernel 1d: batched GEMM  wlog[n][h][m] = qhat_h[n,:] . khat_h[m,:]
// ---------------------------------------------------------------------------
#define QK_P 68
__global__ __launch_bounds__(256) void k_qk(float* __restrict__ ws)
{
  __shared__ __align__(16) float Qs[32*QK_P];   // 8704 B
  __shared__ __align__(16) float Ks[32*QK_P];   // 8704 B

  const int bid = blockIdx.x;
  const int h  = bid >> 6;
  const int nt = (bid >> 3) & 7;
  const int mt = bid & 7;
  const int t  = threadIdx.x;
  const int tc = t & 15, tr = t >> 4;

  const float4* qsrc = (const float4*)(ws + OFF_QH + ((size_t)h*NRES + nt*64)*32);
  const float4* ksrc = (const float4*)(ws + OFF_KH + ((size_t)h*NRES + mt*64)*32);

  #pragma unroll
  for (int u = 0; u < 2; ++u) {
    int idx = t + u*256;            // 0..511
    int r = idx >> 3, j4 = idx & 7;
    float4 qv = qsrc[idx];
    float4 kv = ksrc[idx];
    Qs[(j4*4+0)*QK_P + r] = qv.x;
    Qs[(j4*4+1)*QK_P + r] = qv.y;
    Qs[(j4*4+2)*QK_P + r] = qv.z;
    Qs[(j4*4+3)*QK_P + r] = qv.w;
    Ks[(j4*4+0)*QK_P + r] = kv.x;
    Ks[(j4*4+1)*QK_P + r] = kv.y;
    Ks[(j4*4+2)*QK_P + r] = kv.z;
    Ks[(j4*4+3)*QK_P + r] = kv.w;
  }
  __syncthreads();

  float acc[4][4];
  #pragma unroll
  for (int i=0;i<4;i++)
    #pragma unroll
    for (int k2=0;k2<4;k2++) acc[i][k2]=0.f;

  #pragma unroll
  for (int j = 0; j < 32; ++j) {
    float4 qv = *(const float4*)&Qs[j*QK_P + tr*4];
    float4 kv = *(const float4*)&Ks[j*QK_P + tc*4];
    acc[0][0] += qv.x*kv.x; acc[0][1] += qv.x*kv.y; acc[0][2] += qv.x*kv.z; acc[0][3] += qv.x*kv.w;
    acc[1][0] += qv.y*kv.x; acc[1][1] += qv.y*kv.y; acc[1][2] += qv.y*kv.z; acc[1][3] += qv.y*kv.w;
    acc[2][0] += qv.z*kv.x; acc[2][1] += qv.z*kv.y; acc[2][2] += qv.z*kv.z; acc[2][3] += qv.z*kv.w;
    acc[3][0] += qv.w*kv.x; acc[3][1] += qv.w*kv.y; acc[3][2] += qv.w*kv.z; acc[3][3] += qv.w*kv.w;
  }

  float* wlog = ws + OFF_LOG;
  #pragma unroll
  for (int i = 0; i < 4; ++i) {
    int n = nt*64 + tr*4 + i;
    *(float4*)&wlog[((size_t)n*NH + h)*NRES + mt*64 + tc*4] =
        make_float4(acc[i][0], acc[i][1], acc[i][2], acc[i][3]);
  }
}

// ---------------------------------------------------------------------------
// Kernel 2 (PRIMARY): fused attention, HEAD-SPLIT: 2 blocks per n (grid
// 1024), each owns 6 heads through all phases. Phase A staging = round-10's
// measured-best (16 z/chunk, 8 chunks, ZP=516, pipelined prefetch); FMA loop
// at 6 heads. Occupancy: grid 1024 -> up to 3 blocks/CU (LDS ~46 KB).
// ---------------------------------------------------------------------------
__global__ __launch_bounds__(512) void k_attn2(
    const float* __restrict__ pair,
    const float* __restrict__ rot, const float* __restrict__ trans,
    const float* __restrict__ Wb,
    float* __restrict__ ws)
{
  const int n    = blockIdx.x >> 1;
  const int half = blockIdx.x & 1;
  const int h0   = half*6;           // global head base for this block
  const int t    = threadIdx.x;

  __shared__ __align__(16) float sLogit[6*LROW];    // 12384 B (local heads)
  // union: phase A pair-stage [16][ZP] (33024 B) / C1 sOP[8][6*CZ] (24576 B)
  __shared__ __align__(16) float sU[16*ZP];         // 33024 B
  __shared__ __align__(16) float sOL[6*PV*3];       //   576 B
  __shared__ float sR[9];
  __shared__ float sT[3];

  const float* v    = ws + OFF_V;
  const float* lvp  = ws + OFF_LVP;
  const float* wlog = ws + OFF_LOG;
  float* att = ws + OFF_ATT;

  if (t >= 488 && t < 497)      sR[t-488] = rot[(size_t)n*9 + (t-488)];
  else if (t >= 497 && t < 500) sT[t-497] = trans[(size_t)n*3 + (t-497)];

  // ---------------- Phase A: pipelined staged pair-bias + precomputed qk ---
  {
    float acch[6];
    #pragma unroll
    for (int h=0;h<6;h++)
      acch[h] = wlog[((size_t)n*NH + h0 + h)*NRES + t];   // coalesced qk term

    const float4* pr4 = (const float4*)(pair + (size_t)n*NRES*CZ);

    // prefetch chunk 0 into registers (addresses: idx = t + j*512)
    float4 c0 = pr4[(size_t)((t +    0) >> 2)*32 + 0*4 + (t & 3)];
    float4 c1 = pr4[(size_t)((t +  512) >> 2)*32 + 0*4 + (t & 3)];
    float4 c2 = pr4[(size_t)((t + 1024) >> 2)*32 + 0*4 + (t & 3)];
    float4 c3 = pr4[(size_t)((t + 1536) >> 2)*32 + 0*4 + (t & 3)];

    #pragma unroll 1
    for (int zc = 0; zc < 8; ++zc) {
      __syncthreads();                    // prev chunk's LDS reads done
      {
#define WR_J(CJ, J)                                                   \
        { int idx = t + (J)*512;                                      \
          int row = idx >> 2, q = idx & 3;                            \
          sU[(q*4+0)*ZP + row] = CJ.x;                                \
          sU[(q*4+1)*ZP + row] = CJ.y;                                \
          sU[(q*4+2)*ZP + row] = CJ.z;                                \
          sU[(q*4+3)*ZP + row] = CJ.w; }
        WR_J(c0, 0) WR_J(c1, 1) WR_J(c2, 2) WR_J(c3, 3)
#undef WR_J
      }
      if (zc < 7) {
        c0 = pr4[(size_t)((t +    0) >> 2)*32 + (zc+1)*4 + (t & 3)];
        c1 = pr4[(size_t)((t +  512) >> 2)*32 + (zc+1)*4 + (t & 3)];
        c2 = pr4[(size_t)((t + 1024) >> 2)*32 + (zc+1)*4 + (t & 3)];
        c3 = pr4[(size_t)((t + 1536) >> 2)*32 + (zc+1)*4 + (t & 3)];
      }
      __syncthreads();
      #pragma unroll
      for (int e = 0; e < 16; ++e) {
        float pv = sU[e*ZP + t];
        const float* wrow = Wb + (size_t)(zc*16 + e)*NH + h0;  // wave-uniform
        #pragma unroll
        for (int h=0;h<6;h++) acch[h] += pv * wrow[h];
      }
    }
    #pragma unroll
    for (int h=0;h<6;h++) sLogit[h*LROW + t] = acch[h];
  }
  __syncthreads();

  // ---------------- Phase B: softmax over m, wave per local head -----------
  {
    int wave = t >> 6, lane = t & 63;
    if (wave < 6) {
      int h = wave;
      float x[8]; float mx = -1e30f;
      #pragma unroll
      for (int j=0;j<8;j++) { x[j] = sLogit[h*LROW + lane + j*64]; mx = fmaxf(mx, x[j]); }
      #pragma unroll
      for (int d=1; d<64; d<<=1) mx = fmaxf(mx, __shfl_xor(mx, d, 64));
      float s = 0.f;
      #pragma unroll
      for (int j=0;j<8;j++) { x[j] = __expf(x[j]-mx); s += x[j]; }
      #pragma unroll
      for (int d=1; d<64; d<<=1) s += __shfl_xor(s, d, 64);
      float inv = 1.f/s;
      #pragma unroll
      for (int j=0;j<8;j++) sLogit[h*LROW + lane + j*64] = x[j]*inv;
    }
  }
  __syncthreads();

  // ---------------- Phase C1: o_pair for 6 local heads ---------------------
  // thread = (zq = t&31, hg = (t>>5)&1, mg = t>>6): 3 heads, 64 m's
  {
    const int zq = t & 31;
    const int hg = (t >> 5) & 1;
    const int mg = t >> 6;          // 0..7
    float a0[4] = {0,0,0,0}, a1[4] = {0,0,0,0}, a2[4] = {0,0,0,0};
    const float* pb = pair + (size_t)n*NRES*CZ + zq*4;
    for (int mb = 0; mb < 16; ++mb) {
      int m0 = mg*64 + mb*4;
      float4 w0 = *(const float4*)&sLogit[(hg*3+0)*LROW + m0];
      float4 w1 = *(const float4*)&sLogit[(hg*3+1)*LROW + m0];
      float4 w2 = *(const float4*)&sLogit[(hg*3+2)*LROW + m0];
      const float* w0p = (const float*)&w0;
      const float* w1p = (const float*)&w1;
      const float* w2p = (const float*)&w2;
      #pragma unroll
      for (int i=0;i<4;i++) {
        float4 p4 = *(const float4*)(pb + (size_t)(m0+i)*CZ);
        const float* pp = (const float*)&p4;
        float f0 = w0p[i], f1 = w1p[i], f2 = w2p[i];
        #pragma unroll
        for (int e=0;e<4;e++) {
          a0[e] += f0*pp[e]; a1[e] += f1*pp[e]; a2[e] += f2*pp[e];
        }
      }
    }
    // sOP lives in sU: sOP[mg][lh*CZ + z] = sU[mg*(6*CZ) + ...]
    *(float4*)&sU[mg*(6*CZ) + (hg*3+0)*CZ + zq*4] = make_float4(a0[0],a0[1],a0[2],a0[3]);
    *(float4*)&sU[mg*(6*CZ) + (hg*3+1)*CZ + zq*4] = make_float4(a1[0],a1[1],a1[2],a1[3]);
    *(float4*)&sU[mg*(6*CZ) + (hg*3+2)*CZ + zq*4] = make_float4(a2[0],a2[1],a2[2],a2[3]);
  }

  // ---------------- Phase C2: o_single (t<96) and o_local (96<=t<240) ------
  {
    if (t < 240) {
      float acc = 0.f;
      const float* src; int stride; int off; int lh;
      if (t < 96) { lh = t >> 4;        src = v;   stride = HC;
                    off = (h0 + lh)*CC + (t & 15); }
      else        { int idx = t - 96;   lh = idx/24; src = lvp; stride = HPV3;
                    off = h0*24 + idx; }
      const float* wrow = sLogit + lh*LROW;
      for (int m0 = 0; m0 < NRES; m0 += 4) {
        float4 w4 = *(const float4*)&wrow[m0];
        acc += w4.x * src[(size_t)(m0+0)*stride + off];
        acc += w4.y * src[(size_t)(m0+1)*stride + off];
        acc += w4.z * src[(size_t)(m0+2)*stride + off];
        acc += w4.w * src[(size_t)(m0+3)*stride + off];
      }
      if (t < 96) {
        att[(size_t)n*ATTD + (h0 + lh)*176 + (t & 15)] = acc;
      } else {
        sOL[t-96] = acc;
      }
    }
  }
  __syncthreads();

  for (int o = t; o < 6*CZ; o += 512) {
    float sres = 0.f;
    #pragma unroll
    for (int mg = 0; mg < 8; ++mg) sres += sU[mg*(6*CZ) + o];
    int lh = o >> 7, z = o & 127;
    att[(size_t)n*ATTD + (h0 + lh)*176 + 16 + z] = sres;
  }

  if (t < 48) {
    int lh = t / 8, p = t % 8;
    float x = sOL[lh*24 + p*3 + 0] - sT[0];
    float y = sOL[lh*24 + p*3 + 1] - sT[1];
    float z = sOL[lh*24 + p*3 + 2] - sT[2];
    float o0 = sR[0]*x + sR[3]*y + sR[6]*z;
    float o1 = sR[1]*x + sR[4]*y + sR[7]*z;
    float o2 = sR[2]*x + sR[5]*y + sR[8]*z;
    float nm = sqrtf(o0*o0 + o1*o1 + o2*o2);
    float* ab = att + (size_t)n*ATTD + (h0 + lh)*176;
    ab[144 + p*3 + 0] = o0;
    ab[144 + p*3 + 1] = o1;
    ab[144 + p*3 + 2] = o2;
    ab[168 + p] = nm;
  }
}

// ---------------------------------------------------------------------------
// Kernel 2 (FALLBACK: round-0 fused path, used only if ws too small)
// ---------------------------------------------------------------------------
__global__ __launch_bounds__(512) void k_attn(
    const float* __restrict__ pair,
    const float* __restrict__ rot, const float* __restrict__ trans,
    const float* __restrict__ Wb, const float* __restrict__ scale_head,
    float* __restrict__ ws)
{
  const int n = blockIdx.x;
  const int t = threadIdx.x;

  __shared__ __align__(16) float sLogit[NH*LROW];
  __shared__ __align__(16) float sOP[4][NH*CZ];
  __shared__ __align__(16) float sQ[HC];
  __shared__ __align__(16) float sLQ[HPQ3];
  __shared__ float sSp[NH];
  __shared__ __align__(16) float sOL[HPV3];
  __shared__ float sR[9];
  __shared__ float sT[3];

  const float* q   = ws + OFF_Q;
  const float* k   = ws + OFF_K;
  const float* v   = ws + OFF_V;
  const float* lq  = ws + OFF_LQ;
  const float* lk  = ws + OFF_LK;
  const float* lvp = ws + OFF_LVP;
  float* att = ws + OFF_ATT;

  if (t < 192)               sQ[t]      = q[(size_t)n*HC + t];
  else if (t < 336)          sLQ[t-192] = lq[(size_t)n*HPQ3 + (t-192)];
  else if (t < 348) { float x = scale_head[t-336];
                      sSp[t-336] = (x > 20.f) ? x : log1pf(__expf(x)); }
  else if (t < 357)          sR[t-348]  = rot[(size_t)n*9 + (t-348)];
  else if (t < 360)          sT[t-357]  = trans[(size_t)n*3 + (t-357)];
  __syncthreads();

  {
    const int m = t;
    float acch[NH];
    #pragma unroll
    for (int h=0;h<NH;h++) acch[h]=0.f;

    const float4* pr = (const float4*)(pair + ((size_t)n*NRES + m)*CZ);
    for (int zq = 0; zq < CZ/4; ++zq) {
      float4 p4 = pr[zq];
      const float* pp = (const float*)&p4;
      #pragma unroll
      for (int e=0;e<4;e++) {
        float pv_ = pp[e];
        const float* wrow = Wb + (size_t)(zq*4+e)*NH;
        #pragma unroll
        for (int h=0;h<NH;h++) acch[h] += pv_ * wrow[h];
      }
    }

    #pragma unroll
    for (int h=0;h<NH;h++) {
      const float4* kr = (const float4*)(k + (size_t)m*HC + h*CC);
      const float* qrow = sQ + h*CC;
      float d = 0.f;
      #pragma unroll
      for (int j=0;j<4;j++) {
        float4 k4 = kr[j];
        d += k4.x*qrow[j*4+0] + k4.y*qrow[j*4+1] + k4.z*qrow[j*4+2] + k4.w*qrow[j*4+3];
      }
      acch[h] += SCALE_SINGLE * d;

      const float* lkr = lk + (size_t)m*HPQ3 + h*12;
      const float* lqr = sLQ + h*12;
      float d2 = 0.f;
      #pragma unroll
      for (int j=0;j<12;j++) { float df = lqr[j]-lkr[j]; d2 += df*df; }
      acch[h] += SCALE_FRAME * sSp[h] * d2;

      sLogit[h*LROW + m] = acch[h];
    }
  }
  __syncthreads();

  {
    int wave = t >> 6, lane = t & 63;
    for (int h = wave; h < NH; h += 8) {
      float x[8]; float mx = -1e30f;
      #pragma unroll
      for (int j=0;j<8;j++) { x[j] = sLogit[h*LROW + lane + j*64]; mx = fmaxf(mx, x[j]); }
      #pragma unroll
      for (int d=1; d<64; d<<=1) mx = fmaxf(mx, __shfl_xor(mx, d, 64));
      float s = 0.f;
      #pragma unroll
      for (int j=0;j<8;j++) { x[j] = __expf(x[j]-mx); s += x[j]; }
      #pragma unroll
      for (int d=1; d<64; d<<=1) s += __shfl_xor(s, d, 64);
      float inv = 1.f/s;
      #pragma unroll
      for (int j=0;j<8;j++) sLogit[h*LROW + lane + j*64] = x[j]*inv;
    }
  }
  __syncthreads();

  {
    const int zq = t & 31;
    const int hg = (t >> 5) & 3;
    const int mg = t >> 7;
    float a0[4] = {0,0,0,0}, a1[4] = {0,0,0,0}, a2[4] = {0,0,0,0};
    const float* pb = pair + (size_t)n*NRES*CZ + zq*4;
    for (int mb = 0; mb < 32; ++mb) {
      int m0 = mg*128 + mb*4;
      float4 w0 = *(const float4*)&sLogit[(hg+0)*LROW + m0];
      float4 w1 = *(const float4*)&sLogit[(hg+4)*LROW + m0];
      float4 w2 = *(const float4*)&sLogit[(hg+8)*LROW + m0];
      const float* w0p = (const float*)&w0;
      const float* w1p = (const float*)&w1;
      const float* w2p = (const float*)&w2;
      #pragma unroll
      for (int i=0;i<4;i++) {
        float4 p4 = *(const float4*)(pb + (size_t)(m0+i)*CZ);
        const float* pp = (const float*)&p4;
        float f0 = w0p[i], f1 = w1p[i], f2 = w2p[i];
        #pragma unroll
        for (int e=0;e<4;e++) {
          a0[e] += f0*pp[e]; a1[e] += f1*pp[e]; a2[e] += f2*pp[e];
        }
      }
    }
    *(float4*)&sOP[mg][(hg+0)*CZ + zq*4] = make_float4(a0[0],a0[1],a0[2],a0[3]);
    *(float4*)&sOP[mg][(hg+4)*CZ + zq*4] = make_float4(a1[0],a1[1],a1[2],a1[3]);
    *(float4*)&sOP[mg][(hg+8)*CZ + zq*4] = make_float4(a2[0],a2[1],a2[2],a2[3]);
  }

  {
    if (t < 480) {
      float acc = 0.f;
      const float* src; int stride; int off; int h;
      if (t < 192) { h = t >> 4;        src = v;   stride = HC;   off = t;      }
      else         { int idx = t - 192; h = idx/24; src = lvp; stride = HPV3; off = idx; }
      const float* wrow = sLogit + h*LROW;
      for (int m0 = 0; m0 < NRES; m0 += 4) {
        float4 w4 = *(const float4*)&wrow[m0];
        acc += w4.x * src[(size_t)(m0+0)*stride + off];
        acc += w4.y * src[(size_t)(m0+1)*stride + off];
        acc += w4.z * src[(size_t)(m0+2)*stride + off];
        acc += w4.w * src[(size_t)(m0+3)*stride + off];
      }
      if (t < 192) {
        int h2 = t >> 4;
        att[(size_t)n*ATTD + h2*176 + (t & 15)] = acc;
      } else {
        sOL[t-192] = acc;
      }
    }
  }
  __syncthreads();

  for (int o = t; o < NH*CZ; o += 512) {
    float sres = sOP[0][o] + sOP[1][o] + sOP[2][o] + sOP[3][o];
    int h = o >> 7, z = o & 127;
    att[(size_t)n*ATTD + h*176 + 16 + z] = sres;
  }

  if (t < 96) {
    int h = t / 8, p = t % 8;
    float x = sOL[h*24 + p*3 + 0] - sT[0];
    float y = sOL[h*24 + p*3 + 1] - sT[1];
    float z = sOL[h*24 + p*3 + 2] - sT[2];
    float o0 = sR[0]*x + sR[3]*y + sR[6]*z;
    float o1 = sR[1]*x + sR[4]*y + sR[7]*z;
    float o2 = sR[2]*x + sR[5]*y + sR[8]*z;
    float nm = sqrtf(o0*o0 + o1*o1 + o2*o2);
    float* ab = att + (size_t)n*ATTD + h*176;
    ab[144 + p*3 + 0] = o0;
    ab[144 + p*3 + 1] = o1;
    ab[144 + p*3 + 2] = o2;
    ab[168 + p] = nm;
  }
}

// ---------------------------------------------------------------------------
// Kernel 3: out = att[512,2112] @ Wout[2112,384], K-split tiled GEMM.
// ---------------------------------------------------------------------------
#define KOUT_BK 24

__global__ __launch_bounds__(256) void k_out_part(
    const float* __restrict__ ws, const float* __restrict__ Wout,
    float* __restrict__ part, int KS)
{
  const float* att = ws + OFF_ATT;
  const int bid  = blockIdx.x;
  const int ks   = bid / 48;
  const int tile = bid % 48;
  const int rb   = tile / 6, cb = tile % 6;
  const int KLEN = ATTD / KS;
  const int k0b  = ks * KLEN;

  __shared__ __align__(16) float A_s[64][KOUT_BK+1];
  __shared__ __align__(16) float B_s[KOUT_BK][64];

  const int t  = threadIdx.x;
  const int tc = t & 15, tr = t >> 4;

  float acc[4][4];
  #pragma unroll
  for (int i=0;i<4;i++)
    #pragma unroll
    for (int j=0;j<4;j++) acc[i][j]=0.f;

  for (int k0 = k0b; k0 < k0b + KLEN; k0 += KOUT_BK) {
    __syncthreads();
    #pragma unroll
    for (int j = 0; j < 6; ++j) {
      int idx = t + j*256;
      int r  = idx / KOUT_BK, kk = idx % KOUT_BK;
      A_s[r][kk] = att[(size_t)(rb*64 + r)*ATTD + k0 + kk];
      int kk2 = idx >> 6, c = idx & 63;
      B_s[kk2][c] = Wout[(size_t)(k0 + kk2)*CSZ + cb*64 + c];
    }
    __syncthreads();
    #pragma unroll
    for (int kk = 0; kk < KOUT_BK; ++kk) {
      float4 b4 = *(const float4*)&B_s[kk][tc*4];
      float a0 = A_s[tr*4+0][kk];
      float a1 = A_s[tr*4+1][kk];
      float a2 = A_s[tr*4+2][kk];
      float a3 = A_s[tr*4+3][kk];
      acc[0][0] += a0*b4.x; acc[0][1] += a0*b4.y; acc[0][2] += a0*b4.z; acc[0][3] += a0*b4.w;
      acc[1][0] += a1*b4.x; acc[1][1] += a1*b4.y; acc[1][2] += a1*b4.z; acc[1][3] += a1*b4.w;
      acc[2][0] += a2*b4.x; acc[2][1] += a2*b4.y; acc[2][2] += a2*b4.z; acc[2][3] += a2*b4.w;
      acc[3][0] += a3*b4.x; acc[3][1] += a3*b4.y; acc[3][2] += a3*b4.z; acc[3][3] += a3*b4.w;
    }
  }

  float* pb = part + (size_t)ks*NRES*CSZ;
  #pragma unroll
  for (int i=0;i<4;i++) {
    int row = rb*64 + tr*4 + i;
    int col = cb*64 + tc*4;
    *(float4*)&pb[(size_t)row*CSZ + col] =
        make_float4(acc[i][0], acc[i][1], acc[i][2], acc[i][3]);
  }
}

__global__ __launch_bounds__(256) void k_out_reduce(
    const float* __restrict__ part, const float* __restrict__ bout,
    float* __restrict__ out, int KS)
{
  int idx4 = blockIdx.x*256 + threadIdx.x;
  if (idx4 >= NRES*CSZ/4) return;
  int c4 = idx4 % (CSZ/4);
  float4 s = ((const float4*)bout)[c4];
  const float4* p4 = (const float4*)part;
  for (int ks = 0; ks < KS; ++ks) {
    float4 v = p4[(size_t)ks*(NRES*CSZ/4) + idx4];
    s.x += v.x; s.y += v.y; s.z += v.z; s.w += v.w;
  }
  ((float4*)out)[idx4] = s;
}

__global__ __launch_bounds__(256) void k_out_v1(
    const float* __restrict__ ws, const float* __restrict__ Wout,
    const float* __restrict__ bout, float* __restrict__ out)
{
  const float* att = ws + OFF_ATT;
  int cb = blockIdx.x % 6;
  int rb = blockIdx.x / 6;
  int t  = threadIdx.x;
  int c  = cb*64 + (t & 63);
  int rg = t >> 6;
  int r0 = rb*16;
  float acc[4] = {0.f,0.f,0.f,0.f};
  for (int a = 0; a < ATTD; ++a) {
    float wv = Wout[(size_t)a*CSZ + c];
    #pragma unroll
    for (int i=0;i<4;i++)
      acc[i] += att[(size_t)(r0 + rg + 4*i)*ATTD + a] * wv;
  }
  float b = bout[c];
  #pragma unroll
  for (int i=0;i<4;i++)
    out[(size_t)(r0 + rg + 4*i)*CSZ + c] = acc[i] + b;
}

// ---------------------------------------------------------------------------
extern "C" void kernel_launch(void* const* d_in, const int* in_sizes, int n_in,
                              void* d_out, int out_size, void* d_ws, size_t ws_size,
                              hipStream_t stream) {
  const float* S     = (const float*)d_in[0];
  const float* pair  = (const float*)d_in[1];
  const float* rot   = (const float*)d_in[2];
  const float* trans = (const float*)d_in[3];
  const float* Wq    = (const float*)d_in[4];
  const float* Wk    = (const float*)d_in[5];
  const float* Wv    = (const float*)d_in[6];
  const float* Wqp   = (const float*)d_in[7];
  const float* Wkp   = (const float*)d_in[8];
  const float* Wvp   = (const float*)d_in[9];
  const float* Wb    = (const float*)d_in[10];
  const float* Wout  = (const float*)d_in[11];
  const float* bout  = (const float*)d_in[12];
  const float* sh    = (const float*)d_in[13];
  float* out = (float*)d_out;
  float* ws  = (float*)d_ws;

  hipLaunchKernelGGL(k_proj2,  dim3(16*18), dim3(256), 0, stream,
                     S, Wq, Wk, Wv, Wqp, Wkp, Wvp, ws);
  hipLaunchKernelGGL(k_frames, dim3((NRES*192+255)/256), dim3(256), 0, stream,
                     rot, trans, ws);

  const size_t need_new = (size_t)(OFF_LOG + LOG_FLOATS) * sizeof(float);
  if (ws_size >= need_new) {
    hipLaunchKernelGGL(k_hat,   dim3(NRES), dim3(256), 0, stream, sh, ws);
    hipLaunchKernelGGL(k_qk,    dim3(NH*64), dim3(256), 0, stream, ws);
    hipLaunchKernelGGL(k_attn2, dim3(NRES*2), dim3(512), 0, stream,
                       pair, rot, trans, Wb, ws);
  } else {
    hipLaunchKernelGGL(k_attn,  dim3(NRES), dim3(512), 0, stream,
                       pair, rot, trans, Wb, sh, ws);
  }

  int KS = 0;
  const int cands[4] = {8, 4, 2, 1};
  for (int i = 0; i < 4; ++i) {
    size_t need = ((size_t)OFF_PART + (size_t)cands[i]*NRES*CSZ) * sizeof(float);
    if (need <= ws_size) { KS = cands[i]; break; }
  }
  if (KS > 0) {
    hipLaunchKernelGGL(k_out_part, dim3(48*KS), dim3(256), 0, stream,
                       ws, Wout, ws + OFF_PART, KS);
    hipLaunchKernelGGL(k_out_reduce, dim3((NRES*CSZ/4 + 255)/256), dim3(256), 0, stream,
                       ws + OFF_PART, bout, out, KS);
  } else {
    hipLaunchKernelGGL(k_out_v1, dim3(32*6), dim3(256), 0, stream,
                       ws, Wout, bout, out);
  }
}

// Round 13
// 151.525 us; speedup vs baseline: 1.3573x; 1.3573x over previous
//
#include <hip/hip_runtime.h>
#include <math.h>

// Problem constants
#define NRES 512
#define CSZ  384
#define CZ   128
#define CC   16
#define PQ   4
#define PV   8
#define NH   12

#define HC    (NH*CC)        // 192
#define HPQ3  (NH*PQ*3)      // 144
#define HPV3  (NH*PV*3)      // 288
#define ATTD  (NH*(CZ+CC+PV*4)) // 2112

// workspace layout (floats)
#define OFF_Q   0
#define OFF_K   (OFF_Q  + NRES*HC)     // 98304
#define OFF_V   (OFF_K  + NRES*HC)     // 196608
#define OFF_LQ  (OFF_V  + NRES*HC)     // 294912
#define OFF_LK  (OFF_LQ + NRES*HPQ3)   // 368640
#define OFF_LVP (OFF_LK + NRES*HPQ3)   // 442368
#define OFF_ATT (OFF_LVP+ NRES*HPV3)   // 589824  (512*2112 = 1081344 floats)
#define OFF_LOG (OFF_ATT + NRES*ATTD)  // 1671168: qk-logits [512][12][512]
// partials for the output GEMM reuse the logits region (dead by then)
#define OFF_PART OFF_LOG
#define LOG_FLOATS (NRES*NH*NRES)      // 3145728

// khat/qhat scratch lives in the (not yet written) ATT region:
#define OFF_KH  OFF_ATT
#define OFF_QH  (OFF_ATT + NH*NRES*32)   // +196608

#define SCALE_SINGLE 0.25f
#define SCALE_FRAME  (-0.1178511301977579f)  // -1/sqrt(72)

#define LROW 516   // padded logit row
#define ZP   516   // transposed pair-stage stride (2-way bank alias = free)

// ---------------------------------------------------------------------------
// Kernel 1: projection GEMM  C[512,1152] = S[512,384] @ Wcat[384,1152]
// ---------------------------------------------------------------------------
#define PJ_BM 32
#define PJ_BN 64
#define PJ_BK 32
#define PJ_NK (CSZ/PJ_BK)   // 12
#define PJ_AP 388           // padded A row (floats), mult of 4

__global__ __launch_bounds__(256) void k_proj2(
    const float* __restrict__ S,
    const float* __restrict__ Wq, const float* __restrict__ Wk,
    const float* __restrict__ Wv, const float* __restrict__ Wqp,
    const float* __restrict__ Wkp, const float* __restrict__ Wvp,
    float* __restrict__ ws)
{
  __shared__ __align__(16) float A_s[PJ_BM][PJ_AP];   // 49664 B
  __shared__ __align__(16) float B_s[PJ_BK][PJ_BN];   //  8192 B

  const int t  = threadIdx.x;
  const int rb = blockIdx.x / 18;          // 0..15 row tile
  const int cb = blockIdx.x % 18;          // 0..17 col tile
  const int tc = t & 15, tr = t >> 4;      // micro-tile coords

  #pragma unroll
  for (int j = 0; j < 12; ++j) {
    int idx = t + j*256;
    int row = idx / 96, kq = idx % 96;
    float4 v4 = *(const float4*)(S + (size_t)(rb*PJ_BM + row)*CSZ + kq*4);
    *(float4*)&A_s[row][kq*4] = v4;
  }

  const float* Wp[2]; int ncB[2], lcB[2], kkB[2], cqB[2];
  #pragma unroll
  for (int j = 0; j < 2; ++j) {
    int idx = t + j*256;
    int kk = idx >> 4, cq = idx & 15;
    kkB[j] = kk; cqB[j] = cq;
    int col = cb*PJ_BN + cq*4;
    if      (col < 192) { Wp[j]=Wq;  ncB[j]=192; lcB[j]=col;     }
    else if (col < 384) { Wp[j]=Wk;  ncB[j]=192; lcB[j]=col-192; }
    else if (col < 576) { Wp[j]=Wv;  ncB[j]=192; lcB[j]=col-384; }
    else if (col < 720) { Wp[j]=Wqp; ncB[j]=144; lcB[j]=col-576; }
    else if (col < 864) { Wp[j]=Wkp; ncB[j]=144; lcB[j]=col-720; }
    else                { Wp[j]=Wvp; ncB[j]=288; lcB[j]=col-864; }
  }

  float4 bw[2];
  #pragma unroll
  for (int j = 0; j < 2; ++j)
    bw[j] = *(const float4*)(Wp[j] + (size_t)kkB[j]*ncB[j] + lcB[j]);

  float acc[2][4];
  #pragma unroll
  for (int i=0;i<2;i++)
    #pragma unroll
    for (int jj=0;jj<4;jj++) acc[i][jj]=0.f;

  for (int ki = 0; ki < PJ_NK; ++ki) {
    __syncthreads();
    #pragma unroll
    for (int j = 0; j < 2; ++j)
      *(float4*)&B_s[kkB[j]][cqB[j]*4] = bw[j];
    __syncthreads();

    if (ki + 1 < PJ_NK) {
      #pragma unroll
      for (int j = 0; j < 2; ++j)
        bw[j] = *(const float4*)(Wp[j] + (size_t)((ki+1)*PJ_BK + kkB[j])*ncB[j] + lcB[j]);
    }

    #pragma unroll
    for (int kk4 = 0; kk4 < PJ_BK/4; ++kk4) {
      float4 a0 = *(const float4*)&A_s[tr*2+0][ki*PJ_BK + kk4*4];
      float4 a1 = *(const float4*)&A_s[tr*2+1][ki*PJ_BK + kk4*4];
      const float* a0p = (const float*)&a0;
      const float* a1p = (const float*)&a1;
      #pragma unroll
      for (int e = 0; e < 4; ++e) {
        float4 b4 = *(const float4*)&B_s[kk4*4+e][tc*4];
        float f0 = a0p[e], f1 = a1p[e];
        acc[0][0] += f0*b4.x; acc[0][1] += f0*b4.y; acc[0][2] += f0*b4.z; acc[0][3] += f0*b4.w;
        acc[1][0] += f1*b4.x; acc[1][1] += f1*b4.y; acc[1][2] += f1*b4.z; acc[1][3] += f1*b4.w;
      }
    }
  }

  {
    int col = cb*PJ_BN + tc*4;
    float* dst; int stride; int lcc;
    if      (col < 192) { dst = ws+OFF_Q;   stride=192; lcc=col;     }
    else if (col < 384) { dst = ws+OFF_K;   stride=192; lcc=col-192; }
    else if (col < 576) { dst = ws+OFF_V;   stride=192; lcc=col-384; }
    else if (col < 720) { dst = ws+OFF_LQ;  stride=144; lcc=col-576; }
    else if (col < 864) { dst = ws+OFF_LK;  stride=144; lcc=col-720; }
    else                { dst = ws+OFF_LVP; stride=288; lcc=col-864; }
    #pragma unroll
    for (int i = 0; i < 2; ++i) {
      int row = rb*PJ_BM + tr*2 + i;
      *(float4*)&dst[(size_t)row*stride + lcc] =
          make_float4(acc[i][0], acc[i][1], acc[i][2], acc[i][3]);
    }
  }
}

// ---------------------------------------------------------------------------
// Kernel 1b: apply rigid frames in place to qp, kp, vp -> lq, lk, lvp
// ---------------------------------------------------------------------------
__global__ __launch_bounds__(256) void k_frames(
    const float* __restrict__ rot, const float* __restrict__ trans,
    float* __restrict__ ws)
{
  int gid = blockIdx.x*256 + threadIdx.x;
  if (gid >= NRES*192) return;
  int m = gid / 192;
  int rest = gid % 192;
  float* base; int pidx;
  if      (rest <  48) { base = ws + OFF_LQ  + (size_t)m*HPQ3; pidx = rest;     }
  else if (rest <  96) { base = ws + OFF_LK  + (size_t)m*HPQ3; pidx = rest-48;  }
  else                 { base = ws + OFF_LVP + (size_t)m*HPV3; pidx = rest-96;  }
  float x = base[pidx*3+0], y = base[pidx*3+1], z = base[pidx*3+2];
  const float* R = rot + (size_t)m*9;
  const float* T = trans + (size_t)m*3;
  float o0 = R[0]*x + R[1]*y + R[2]*z + T[0];
  float o1 = R[3]*x + R[4]*y + R[5]*z + T[1];
  float o2 = R[6]*x + R[7]*y + R[8]*z + T[2];
  base[pidx*3+0]=o0; base[pidx*3+1]=o1; base[pidx*3+2]=o2;
}

// ---------------------------------------------------------------------------
// Kernel 1c: build khat[h][m][32] and qhat[h][n][32] (correctness-proven).
//   qhat = [SCALE_SINGLE*q, -2*SF*sp*lq, 1, 0,0,0]
//   khat = [k,              lk,          SF*sp*|lk|^2, 0,0,0]
// ---------------------------------------------------------------------------
__global__ __launch_bounds__(256) void k_hat(
    const float* __restrict__ scale_head, float* __restrict__ ws)
{
  const int r = blockIdx.x;
  const int t = threadIdx.x;
  __shared__ float sSp[NH];
  if (t < NH) { float x = scale_head[t];
                sSp[t] = (x > 20.f) ? x : log1pf(__expf(x)); }
  __syncthreads();

  for (int i = t; i < NH*32; i += 256) {
    const int h = i >> 5, j = i & 31;
    const float* kk = ws + OFF_K  + (size_t)r*HC   + h*CC;
    const float* lk = ws + OFF_LK + (size_t)r*HPQ3 + h*12;
    const float* qq = ws + OFF_Q  + (size_t)r*HC   + h*CC;
    const float* lq = ws + OFF_LQ + (size_t)r*HPQ3 + h*12;
    float kv, qv;
    if (j < 16)      { kv = kk[j];    qv = SCALE_SINGLE * qq[j]; }
    else if (j < 28) { kv = lk[j-16]; qv = -2.f*SCALE_FRAME*sSp[h]*lq[j-16]; }
    else if (j == 28) {
      float s2 = 0.f;
      #pragma unroll
      for (int e=0;e<12;e++) { float v = lk[e]; s2 += v*v; }
      kv = SCALE_FRAME * sSp[h] * s2;
      qv = 1.f;
    } else { kv = 0.f; qv = 0.f; }
    ws[OFF_KH + ((size_t)h*NRES + r)*32 + j] = kv;
    ws[OFF_QH + ((size_t)h*NRES + r)*32 + j] = qv;
  }
}

// ---------------------------------------------------------------------------
// Kernel 1d: batched GEMM  wlog[n][h][m] = qhat_h[n,:] . khat_h[m,:]
// ---------------------------------------------------------------------------
#define QK_P 68
__global__ __launch_bounds__(256) void k_qk(float* __restrict__ ws)
{
  __shared__ __align__(16) float Qs[32*QK_P];   // 8704 B
  __shared__ __align__(16) float Ks[32*QK_P];   // 8704 B

  const int bid = blockIdx.x;
  const int h  = bid >> 6;
  const int nt = (bid >> 3) & 7;
  const int mt = bid & 7;
  const int t  = threadIdx.x;
  const int tc = t & 15, tr = t >> 4;

  const float4* qsrc = (const float4*)(ws + OFF_QH + ((size_t)h*NRES + nt*64)*32);
  const float4* ksrc = (const float4*)(ws + OFF_KH + ((size_t)h*NRES + mt*64)*32);

  #pragma unroll
  for (int u = 0; u < 2; ++u) {
    int idx = t + u*256;            // 0..511
    int r = idx >> 3, j4 = idx & 7;
    float4 qv = qsrc[idx];
    float4 kv = ksrc[idx];
    Qs[(j4*4+0)*QK_P + r] = qv.x;
    Qs[(j4*4+1)*QK_P + r] = qv.y;
    Qs[(j4*4+2)*QK_P + r] = qv.z;
    Qs[(j4*4+3)*QK_P + r] = qv.w;
    Ks[(j4*4+0)*QK_P + r] = kv.x;
    Ks[(j4*4+1)*QK_P + r] = kv.y;
    Ks[(j4*4+2)*QK_P + r] = kv.z;
    Ks[(j4*4+3)*QK_P + r] = kv.w;
  }
  __syncthreads();

  float acc[4][4];
  #pragma unroll
  for (int i=0;i<4;i++)
    #pragma unroll
    for (int k2=0;k2<4;k2++) acc[i][k2]=0.f;

  #pragma unroll
  for (int j = 0; j < 32; ++j) {
    float4 qv = *(const float4*)&Qs[j*QK_P + tr*4];
    float4 kv = *(const float4*)&Ks[j*QK_P + tc*4];
    acc[0][0] += qv.x*kv.x; acc[0][1] += qv.x*kv.y; acc[0][2] += qv.x*kv.z; acc[0][3] += qv.x*kv.w;
    acc[1][0] += qv.y*kv.x; acc[1][1] += qv.y*kv.y; acc[1][2] += qv.y*kv.z; acc[1][3] += qv.y*kv.w;
    acc[2][0] += qv.z*kv.x; acc[2][1] += qv.z*kv.y; acc[2][2] += qv.z*kv.z; acc[2][3] += qv.z*kv.w;
    acc[3][0] += qv.w*kv.x; acc[3][1] += qv.w*kv.y; acc[3][2] += qv.w*kv.z; acc[3][3] += qv.w*kv.w;
  }

  float* wlog = ws + OFF_LOG;
  #pragma unroll
  for (int i = 0; i < 4; ++i) {
    int n = nt*64 + tr*4 + i;
    *(float4*)&wlog[((size_t)n*NH + h)*NRES + mt*64 + tc*4] =
        make_float4(acc[i][0], acc[i][1], acc[i][2], acc[i][3]);
  }
}

// ---------------------------------------------------------------------------
// Kernel 2 (PRIMARY): fused attention. Phase A = round-10 measured-best:
// transposed LDS staging (ZP=516, 2-way bank alias = free), 16 z/chunk,
// 8 chunks, register-pipelined prefetch (k_proj2's proven pattern).
// ---------------------------------------------------------------------------
__global__ __launch_bounds__(512) void k_attn2(
    const float* __restrict__ pair,
    const float* __restrict__ rot, const float* __restrict__ trans,
    const float* __restrict__ Wb,
    float* __restrict__ ws)
{
  const int n = blockIdx.x;
  const int t = threadIdx.x;

  __shared__ __align__(16) float sLogit[NH*LROW];   // 24768 B
  // union: phase A pair-stage [16][ZP] (33024 B) / phase C1 sOP[4][NH*CZ] (24576 B)
  __shared__ __align__(16) float sU[16*ZP];         // 33024 B
  __shared__ __align__(16) float sOL[HPV3];
  __shared__ float sR[9];
  __shared__ float sT[3];

  const float* v    = ws + OFF_V;
  const float* lvp  = ws + OFF_LVP;
  const float* wlog = ws + OFF_LOG;
  float* att = ws + OFF_ATT;

  if (t >= 488 && t < 497)      sR[t-488] = rot[(size_t)n*9 + (t-488)];
  else if (t >= 497 && t < 500) sT[t-497] = trans[(size_t)n*3 + (t-497)];

  // ---------------- Phase A: pipelined staged pair-bias + precomputed qk ---
  {
    float acch[NH];
    #pragma unroll
    for (int h=0;h<NH;h++)
      acch[h] = wlog[((size_t)n*NH + h)*NRES + t];   // coalesced qk term

    const float4* pr4 = (const float4*)(pair + (size_t)n*NRES*CZ);

    // prefetch chunk 0 into registers (addresses: idx = t + j*512)
    float4 c0 = pr4[(size_t)((t +    0) >> 2)*32 + 0*4 + (t & 3)];
    float4 c1 = pr4[(size_t)((t +  512) >> 2)*32 + 0*4 + (t & 3)];
    float4 c2 = pr4[(size_t)((t + 1024) >> 2)*32 + 0*4 + (t & 3)];
    float4 c3 = pr4[(size_t)((t + 1536) >> 2)*32 + 0*4 + (t & 3)];

    #pragma unroll 1
    for (int zc = 0; zc < 8; ++zc) {
      __syncthreads();                    // prev chunk's LDS reads done
      // write staged regs, transposed: sU[zwithin*ZP + row]
      {
#define WR_J(CJ, J)                                                   \
        { int idx = t + (J)*512;                                      \
          int row = idx >> 2, q = idx & 3;                            \
          sU[(q*4+0)*ZP + row] = CJ.x;                                \
          sU[(q*4+1)*ZP + row] = CJ.y;                                \
          sU[(q*4+2)*ZP + row] = CJ.z;                                \
          sU[(q*4+3)*ZP + row] = CJ.w; }
        WR_J(c0, 0) WR_J(c1, 1) WR_J(c2, 2) WR_J(c3, 3)
#undef WR_J
      }
      // prefetch next chunk (latency hidden under compute below)
      if (zc < 7) {
        c0 = pr4[(size_t)((t +    0) >> 2)*32 + (zc+1)*4 + (t & 3)];
        c1 = pr4[(size_t)((t +  512) >> 2)*32 + (zc+1)*4 + (t & 3)];
        c2 = pr4[(size_t)((t + 1024) >> 2)*32 + (zc+1)*4 + (t & 3)];
        c3 = pr4[(size_t)((t + 1536) >> 2)*32 + (zc+1)*4 + (t & 3)];
      }
      __syncthreads();
      // compute: z wave-uniform -> Wb via s_load; LDS reads lane-consecutive
      #pragma unroll
      for (int e = 0; e < 16; ++e) {
        float pv = sU[e*ZP + t];
        const float* wrow = Wb + (size_t)(zc*16 + e)*NH;
        #pragma unroll
        for (int h=0;h<NH;h++) acch[h] += pv * wrow[h];
      }
    }
    #pragma unroll
    for (int h=0;h<NH;h++) sLogit[h*LROW + t] = acch[h];
  }
  __syncthreads();

  // ---------------- Phase B: softmax over m, wave per head -----------------
  {
    int wave = t >> 6, lane = t & 63;
    for (int h = wave; h < NH; h += 8) {
      float x[8]; float mx = -1e30f;
      #pragma unroll
      for (int j=0;j<8;j++) { x[j] = sLogit[h*LROW + lane + j*64]; mx = fmaxf(mx, x[j]); }
      #pragma unroll
      for (int d=1; d<64; d<<=1) mx = fmaxf(mx, __shfl_xor(mx, d, 64));
      float s = 0.f;
      #pragma unroll
      for (int j=0;j<8;j++) { x[j] = __expf(x[j]-mx); s += x[j]; }
      #pragma unroll
      for (int d=1; d<64; d<<=1) s += __shfl_xor(s, d, 64);
      float inv = 1.f/s;
      #pragma unroll
      for (int j=0;j<8;j++) sLogit[h*LROW + lane + j*64] = x[j]*inv;
    }
  }
  __syncthreads();

  // ---------------- Phase C1: o_pair (second pair read, cache-served) ------
  {
    const int zq = t & 31;
    const int hg = (t >> 5) & 3;
    const int mg = t >> 7;
    float a0[4] = {0,0,0,0}, a1[4] = {0,0,0,0}, a2[4] = {0,0,0,0};
    const float* pb = pair + (size_t)n*NRES*CZ + zq*4;
    for (int mb = 0; mb < 32; ++mb) {
      int m0 = mg*128 + mb*4;
      float4 w0 = *(const float4*)&sLogit[(hg+0)*LROW + m0];
      float4 w1 = *(const float4*)&sLogit[(hg+4)*LROW + m0];
      float4 w2 = *(const float4*)&sLogit[(hg+8)*LROW + m0];
      const float* w0p = (const float*)&w0;
      const float* w1p = (const float*)&w1;
      const float* w2p = (const float*)&w2;
      #pragma unroll
      for (int i=0;i<4;i++) {
        float4 p4 = *(const float4*)(pb + (size_t)(m0+i)*CZ);
        const float* pp = (const float*)&p4;
        float f0 = w0p[i], f1 = w1p[i], f2 = w2p[i];
        #pragma unroll
        for (int e=0;e<4;e++) {
          a0[e] += f0*pp[e]; a1[e] += f1*pp[e]; a2[e] += f2*pp[e];
        }
      }
    }
    // sOP lives in sU: sOP[mg][idx] = sU[mg*(NH*CZ) + idx]
    *(float4*)&sU[mg*(NH*CZ) + (hg+0)*CZ + zq*4] = make_float4(a0[0],a0[1],a0[2],a0[3]);
    *(float4*)&sU[mg*(NH*CZ) + (hg+4)*CZ + zq*4] = make_float4(a1[0],a1[1],a1[2],a1[3]);
    *(float4*)&sU[mg*(NH*CZ) + (hg+8)*CZ + zq*4] = make_float4(a2[0],a2[1],a2[2],a2[3]);
  }

  // ---------------- Phase C2: o_single (t<192) and o_local (192<=t<480) ----
  {
    if (t < 480) {
      float acc = 0.f;
      const float* src; int stride; int off; int h;
      if (t < 192) { h = t >> 4;        src = v;   stride = HC;   off = t;      }
      else         { int idx = t - 192; h = idx/24; src = lvp; stride = HPV3; off = idx; }
      const float* wrow = sLogit + h*LROW;
      for (int m0 = 0; m0 < NRES; m0 += 4) {
        float4 w4 = *(const float4*)&wrow[m0];
        acc += w4.x * src[(size_t)(m0+0)*stride + off];
        acc += w4.y * src[(size_t)(m0+1)*stride + off];
        acc += w4.z * src[(size_t)(m0+2)*stride + off];
        acc += w4.w * src[(size_t)(m0+3)*stride + off];
      }
      if (t < 192) {
        int h2 = t >> 4;
        att[(size_t)n*ATTD + h2*176 + (t & 15)] = acc;
      } else {
        sOL[t-192] = acc;
      }
    }
  }
  __syncthreads();

  for (int o = t; o < NH*CZ; o += 512) {
    float sres = sU[0*(NH*CZ) + o] + sU[1*(NH*CZ) + o]
               + sU[2*(NH*CZ) + o] + sU[3*(NH*CZ) + o];
    int h = o >> 7, z = o & 127;
    att[(size_t)n*ATTD + h*176 + 16 + z] = sres;
  }

  if (t < 96) {
    int h = t / 8, p = t % 8;
    float x = sOL[h*24 + p*3 + 0] - sT[0];
    float y = sOL[h*24 + p*3 + 1] - sT[1];
    float z = sOL[h*24 + p*3 + 2] - sT[2];
    float o0 = sR[0]*x + sR[3]*y + sR[6]*z;
    float o1 = sR[1]*x + sR[4]*y + sR[7]*z;
    float o2 = sR[2]*x + sR[5]*y + sR[8]*z;
    float nm = sqrtf(o0*o0 + o1*o1 + o2*o2);
    float* ab = att + (size_t)n*ATTD + h*176;
    ab[144 + p*3 + 0] = o0;
    ab[144 + p*3 + 1] = o1;
    ab[144 + p*3 + 2] = o2;
    ab[168 + p] = nm;
  }
}

// ---------------------------------------------------------------------------
// Kernel 2 (FALLBACK: round-0 fused path, used only if ws too small)
// ---------------------------------------------------------------------------
__global__ __launch_bounds__(512) void k_attn(
    const float* __restrict__ pair,
    const float* __restrict__ rot, const float* __restrict__ trans,
    const float* __restrict__ Wb, const float* __restrict__ scale_head,
    float* __restrict__ ws)
{
  const int n = blockIdx.x;
  const int t = threadIdx.x;

  __shared__ __align__(16) float sLogit[NH*LROW];
  __shared__ __align__(16) float sOP[4][NH*CZ];
  __shared__ __align__(16) float sQ[HC];
  __shared__ __align__(16) float sLQ[HPQ3];
  __shared__ float sSp[NH];
  __shared__ __align__(16) float sOL[HPV3];
  __shared__ float sR[9];
  __shared__ float sT[3];

  const float* q   = ws + OFF_Q;
  const float* k   = ws + OFF_K;
  const float* v   = ws + OFF_V;
  const float* lq  = ws + OFF_LQ;
  const float* lk  = ws + OFF_LK;
  const float* lvp = ws + OFF_LVP;
  float* att = ws + OFF_ATT;

  if (t < 192)               sQ[t]      = q[(size_t)n*HC + t];
  else if (t < 336)          sLQ[t-192] = lq[(size_t)n*HPQ3 + (t-192)];
  else if (t < 348) { float x = scale_head[t-336];
                      sSp[t-336] = (x > 20.f) ? x : log1pf(__expf(x)); }
  else if (t < 357)          sR[t-348]  = rot[(size_t)n*9 + (t-348)];
  else if (t < 360)          sT[t-357]  = trans[(size_t)n*3 + (t-357)];
  __syncthreads();

  {
    const int m = t;
    float acch[NH];
    #pragma unroll
    for (int h=0;h<NH;h++) acch[h]=0.f;

    const float4* pr = (const float4*)(pair + ((size_t)n*NRES + m)*CZ);
    for (int zq = 0; zq < CZ/4; ++zq) {
      float4 p4 = pr[zq];
      const float* pp = (const float*)&p4;
      #pragma unroll
      for (int e=0;e<4;e++) {
        float pv_ = pp[e];
        const float* wrow = Wb + (size_t)(zq*4+e)*NH;
        #pragma unroll
        for (int h=0;h<NH;h++) acch[h] += pv_ * wrow[h];
      }
    }

    #pragma unroll
    for (int h=0;h<NH;h++) {
      const float4* kr = (const float4*)(k + (size_t)m*HC + h*CC);
      const float* qrow = sQ + h*CC;
      float d = 0.f;
      #pragma unroll
      for (int j=0;j<4;j++) {
        float4 k4 = kr[j];
        d += k4.x*qrow[j*4+0] + k4.y*qrow[j*4+1] + k4.z*qrow[j*4+2] + k4.w*qrow[j*4+3];
      }
      acch[h] += SCALE_SINGLE * d;

      const float* lkr = lk + (size_t)m*HPQ3 + h*12;
      const float* lqr = sLQ + h*12;
      float d2 = 0.f;
      #pragma unroll
      for (int j=0;j<12;j++) { float df = lqr[j]-lkr[j]; d2 += df*df; }
      acch[h] += SCALE_FRAME * sSp[h] * d2;

      sLogit[h*LROW + m] = acch[h];
    }
  }
  __syncthreads();

  {
    int wave = t >> 6, lane = t & 63;
    for (int h = wave; h < NH; h += 8) {
      float x[8]; float mx = -1e30f;
      #pragma unroll
      for (int j=0;j<8;j++) { x[j] = sLogit[h*LROW + lane + j*64]; mx = fmaxf(mx, x[j]); }
      #pragma unroll
      for (int d=1; d<64; d<<=1) mx = fmaxf(mx, __shfl_xor(mx, d, 64));
      float s = 0.f;
      #pragma unroll
      for (int j=0;j<8;j++) { x[j] = __expf(x[j]-mx); s += x[j]; }
      #pragma unroll
      for (int d=1; d<64; d<<=1) s += __shfl_xor(s, d, 64);
      float inv = 1.f/s;
      #pragma unroll
      for (int j=0;j<8;j++) sLogit[h*LROW + lane + j*64] = x[j]*inv;
    }
  }
  __syncthreads();

  {
    const int zq = t & 31;
    const int hg = (t >> 5) & 3;
    const int mg = t >> 7;
    float a0[4] = {0,0,0,0}, a1[4] = {0,0,0,0}, a2[4] = {0,0,0,0};
    const float* pb = pair + (size_t)n*NRES*CZ + zq*4;
    for (int mb = 0; mb < 32; ++mb) {
      int m0 = mg*128 + mb*4;
      float4 w0 = *(const float4*)&sLogit[(hg+0)*LROW + m0];
      float4 w1 = *(const float4*)&sLogit[(hg+4)*LROW + m0];
      float4 w2 = *(const float4*)&sLogit[(hg+8)*LROW + m0];
      const float* w0p = (const float*)&w0;
      const float* w1p = (const float*)&w1;
      const float* w2p = (const float*)&w2;
      #pragma unroll
      for (int i=0;i<4;i++) {
        float4 p4 = *(const float4*)(pb + (size_t)(m0+i)*CZ);
        const float* pp = (const float*)&p4;
        float f0 = w0p[i], f1 = w1p[i], f2 = w2p[i];
        #pragma unroll
        for (int e=0;e<4;e++) {
          a0[e] += f0*pp[e]; a1[e] += f1*pp[e]; a2[e] += f2*pp[e];
        }
      }
    }
    *(float4*)&sOP[mg][(hg+0)*CZ + zq*4] = make_float4(a0[0],a0[1],a0[2],a0[3]);
    *(float4*)&sOP[mg][(hg+4)*CZ + zq*4] = make_float4(a1[0],a1[1],a1[2],a1[3]);
    *(float4*)&sOP[mg][(hg+8)*CZ + zq*4] = make_float4(a2[0],a2[1],a2[2],a2[3]);
  }

  {
    if (t < 480) {
      float acc = 0.f;
      const float* src; int stride; int off; int h;
      if (t < 192) { h = t >> 4;        src = v;   stride = HC;   off = t;      }
      else         { int idx = t - 192; h = idx/24; src = lvp; stride = HPV3; off = idx; }
      const float* wrow = sLogit + h*LROW;
      for (int m0 = 0; m0 < NRES; m0 += 4) {
        float4 w4 = *(const float4*)&wrow[m0];
        acc += w4.x * src[(size_t)(m0+0)*stride + off];
        acc += w4.y * src[(size_t)(m0+1)*stride + off];
        acc += w4.z * src[(size_t)(m0+2)*stride + off];
        acc += w4.w * src[(size_t)(m0+3)*stride + off];
      }
      if (t < 192) {
        int h2 = t >> 4;
        att[(size_t)n*ATTD + h2*176 + (t & 15)] = acc;
      } else {
        sOL[t-192] = acc;
      }
    }
  }
  __syncthreads();

  for (int o = t; o < NH*CZ; o += 512) {
    float sres = sOP[0][o] + sOP[1][o] + sOP[2][o] + sOP[3][o];
    int h = o >> 7, z = o & 127;
    att[(size_t)n*ATTD + h*176 + 16 + z] = sres;
  }

  if (t < 96) {
    int h = t / 8, p = t % 8;
    float x = sOL[h*24 + p*3 + 0] - sT[0];
    float y = sOL[h*24 + p*3 + 1] - sT[1];
    float z = sOL[h*24 + p*3 + 2] - sT[2];
    float o0 = sR[0]*x + sR[3]*y + sR[6]*z;
    float o1 = sR[1]*x + sR[4]*y + sR[7]*z;
    float o2 = sR[2]*x + sR[5]*y + sR[8]*z;
    float nm = sqrtf(o0*o0 + o1*o1 + o2*o2);
    float* ab = att + (size_t)n*ATTD + h*176;
    ab[144 + p*3 + 0] = o0;
    ab[144 + p*3 + 1] = o1;
    ab[144 + p*3 + 2] = o2;
    ab[168 + p] = nm;
  }
}

// ---------------------------------------------------------------------------
// Kernel 3: out = att[512,2112] @ Wout[2112,384], K-split tiled GEMM.
// ---------------------------------------------------------------------------
#define KOUT_BK 24

__global__ __launch_bounds__(256) void k_out_part(
    const float* __restrict__ ws, const float* __restrict__ Wout,
    float* __restrict__ part, int KS)
{
  const float* att = ws + OFF_ATT;
  const int bid  = blockIdx.x;
  const int ks   = bid / 48;
  const int tile = bid % 48;
  const int rb   = tile / 6, cb = tile % 6;
  const int KLEN = ATTD / KS;
  const int k0b  = ks * KLEN;

  __shared__ __align__(16) float A_s[64][KOUT_BK+1];
  __shared__ __align__(16) float B_s[KOUT_BK][64];

  const int t  = threadIdx.x;
  const int tc = t & 15, tr = t >> 4;

  float acc[4][4];
  #pragma unroll
  for (int i=0;i<4;i++)
    #pragma unroll
    for (int j=0;j<4;j++) acc[i][j]=0.f;

  for (int k0 = k0b; k0 < k0b + KLEN; k0 += KOUT_BK) {
    __syncthreads();
    #pragma unroll
    for (int j = 0; j < 6; ++j) {
      int idx = t + j*256;
      int r  = idx / KOUT_BK, kk = idx % KOUT_BK;
      A_s[r][kk] = att[(size_t)(rb*64 + r)*ATTD + k0 + kk];
      int kk2 = idx >> 6, c = idx & 63;
      B_s[kk2][c] = Wout[(size_t)(k0 + kk2)*CSZ + cb*64 + c];
    }
    __syncthreads();
    #pragma unroll
    for (int kk = 0; kk < KOUT_BK; ++kk) {
      float4 b4 = *(const float4*)&B_s[kk][tc*4];
      float a0 = A_s[tr*4+0][kk];
      float a1 = A_s[tr*4+1][kk];
      float a2 = A_s[tr*4+2][kk];
      float a3 = A_s[tr*4+3][kk];
      acc[0][0] += a0*b4.x; acc[0][1] += a0*b4.y; acc[0][2] += a0*b4.z; acc[0][3] += a0*b4.w;
      acc[1][0] += a1*b4.x; acc[1][1] += a1*b4.y; acc[1][2] += a1*b4.z; acc[1][3] += a1*b4.w;
      acc[2][0] += a2*b4.x; acc[2][1] += a2*b4.y; acc[2][2] += a2*b4.z; acc[2][3] += a2*b4.w;
      acc[3][0] += a3*b4.x; acc[3][1] += a3*b4.y; acc[3][2] += a3*b4.z; acc[3][3] += a3*b4.w;
    }
  }

  float* pb = part + (size_t)ks*NRES*CSZ;
  #pragma unroll
  for (int i=0;i<4;i++) {
    int row = rb*64 + tr*4 + i;
    int col = cb*64 + tc*4;
    *(float4*)&pb[(size_t)row*CSZ + col] =
        make_float4(acc[i][0], acc[i][1], acc[i][2], acc[i][3]);
  }
}

__global__ __launch_bounds__(256) void k_out_reduce(
    const float* __restrict__ part, const float* __restrict__ bout,
    float* __restrict__ out, int KS)
{
  int idx4 = blockIdx.x*256 + threadIdx.x;
  if (idx4 >= NRES*CSZ/4) return;
  int c4 = idx4 % (CSZ/4);
  float4 s = ((const float4*)bout)[c4];
  const float4* p4 = (const float4*)part;
  for (int ks = 0; ks < KS; ++ks) {
    float4 v = p4[(size_t)ks*(NRES*CSZ/4) + idx4];
    s.x += v.x; s.y += v.y; s.z += v.z; s.w += v.w;
  }
  ((float4*)out)[idx4] = s;
}

__global__ __launch_bounds__(256) void k_out_v1(
    const float* __restrict__ ws, const float* __restrict__ Wout,
    const float* __restrict__ bout, float* __restrict__ out)
{
  const float* att = ws + OFF_ATT;
  int cb = blockIdx.x % 6;
  int rb = blockIdx.x / 6;
  int t  = threadIdx.x;
  int c  = cb*64 + (t & 63);
  int rg = t >> 6;
  int r0 = rb*16;
  float acc[4] = {0.f,0.f,0.f,0.f};
  for (int a = 0; a < ATTD; ++a) {
    float wv = Wout[(size_t)a*CSZ + c];
    #pragma unroll
    for (int i=0;i<4;i++)
      acc[i] += att[(size_t)(r0 + rg + 4*i)*ATTD + a] * wv;
  }
  float b = bout[c];
  #pragma unroll
  for (int i=0;i<4;i++)
    out[(size_t)(r0 + rg + 4*i)*CSZ + c] = acc[i] + b;
}

// ---------------------------------------------------------------------------
extern "C" void kernel_launch(void* const* d_in, const int* in_sizes, int n_in,
                              void* d_out, int out_size, void* d_ws, size_t ws_size,
                              hipStream_t stream) {
  const float* S     = (const float*)d_in[0];
  const float* pair  = (const float*)d_in[1];
  const float* rot   = (const float*)d_in[2];
  const float* trans = (const float*)d_in[3];
  const float* Wq    = (const float*)d_in[4];
  const float* Wk    = (const float*)d_in[5];
  const float* Wv    = (const float*)d_in[6];
  const float* Wqp   = (const float*)d_in[7];
  const float* Wkp   = (const float*)d_in[8];
  const float* Wvp   = (const float*)d_in[9];
  const float* Wb    = (const float*)d_in[10];
  const float* Wout  = (const float*)d_in[11];
  const float* bout  = (const float*)d_in[12];
  const float* sh    = (const float*)d_in[13];
  float* out = (float*)d_out;
  float* ws  = (float*)d_ws;

  hipLaunchKernelGGL(k_proj2,  dim3(16*18), dim3(256), 0, stream,
                     S, Wq, Wk, Wv, Wqp, Wkp, Wvp, ws);
  hipLaunchKernelGGL(k_frames, dim3((NRES*192+255)/256), dim3(256), 0, stream,
                     rot, trans, ws);

  const size_t need_new = (size_t)(OFF_LOG + LOG_FLOATS) * sizeof(float);
  if (ws_size >= need_new) {
    hipLaunchKernelGGL(k_hat,   dim3(NRES), dim3(256), 0, stream, sh, ws);
    hipLaunchKernelGGL(k_qk,    dim3(NH*64), dim3(256), 0, stream, ws);
    hipLaunchKernelGGL(k_attn2, dim3(NRES), dim3(512), 0, stream,
                       pair, rot, trans, Wb, ws);
  } else {
    hipLaunchKernelGGL(k_attn,  dim3(NRES), dim3(512), 0, stream,
                       pair, rot, trans, Wb, sh, ws);
  }

  int KS = 0;
  const int cands[4] = {8, 4, 2, 1};
  for (int i = 0; i < 4; ++i) {
    size_t need = ((size_t)OFF_PART + (size_t)cands[i]*NRES*CSZ) * sizeof(float);
    if (need <= ws_size) { KS = cands[i]; break; }
  }
  if (KS > 0) {
    hipLaunchKernelGGL(k_out_part, dim3(48*KS), dim3(256), 0, stream,
                       ws, Wout, ws + OFF_PART, KS);
    hipLaunchKernelGGL(k_out_reduce, dim3((NRES*CSZ/4 + 255)/256), dim3(256), 0, stream,
                       ws + OFF_PART, bout, out, KS);
  } else {
    hipLaunchKernelGGL(k_out_v1, dim3(32*6), dim3(256), 0, stream,
                       ws, Wout, bout, out);
  }
}

// Round 14
// 142.368 us; speedup vs baseline: 1.4445x; 1.0643x over previous
//
#include <hip/hip_runtime.h>
#include <math.h>

// Problem constants
#define NRES 512
#define CSZ  384
#define CZ   128
#define CC   16
#define PQ   4
#define PV   8
#define NH   12

#define HC    (NH*CC)        // 192
#define HPQ3  (NH*PQ*3)      // 144
#define HPV3  (NH*PV*3)      // 288
#define ATTD  (NH*(CZ+CC+PV*4)) // 2112

// workspace layout (floats)
#define OFF_Q   0
#define OFF_K   (OFF_Q  + NRES*HC)     // 98304
#define OFF_V   (OFF_K  + NRES*HC)     // 196608
#define OFF_LQ  (OFF_V  + NRES*HC)     // 294912
#define OFF_LK  (OFF_LQ + NRES*HPQ3)   // 368640
#define OFF_LVP (OFF_LK + NRES*HPQ3)   // 442368
#define OFF_ATT (OFF_LVP+ NRES*HPV3)   // 589824  (512*2112 = 1081344 floats)
#define OFF_LOG (OFF_ATT + NRES*ATTD)  // 1671168: qk-logits [512][12][512]
// partials for the output GEMM reuse the logits region (dead by then)
#define OFF_PART OFF_LOG
#define LOG_FLOATS (NRES*NH*NRES)      // 3145728

// khat/qhat scratch lives in the (not yet written) ATT region:
#define OFF_KH  OFF_ATT
#define OFF_QH  (OFF_ATT + NH*NRES*32)   // +196608

#define SCALE_SINGLE 0.25f
#define SCALE_FRAME  (-0.1178511301977579f)  // -1/sqrt(72)

#define LROW 516   // padded logit row
#define ZP   516   // transposed pair-stage stride (2-way bank alias = free)

// ---------------------------------------------------------------------------
// Kernel 1: projection GEMM  C[512,1152] = S[512,384] @ Wcat[384,1152]
// ---------------------------------------------------------------------------
#define PJ_BM 32
#define PJ_BN 64
#define PJ_BK 32
#define PJ_NK (CSZ/PJ_BK)   // 12
#define PJ_AP 388           // padded A row (floats), mult of 4

__global__ __launch_bounds__(256) void k_proj2(
    const float* __restrict__ S,
    const float* __restrict__ Wq, const float* __restrict__ Wk,
    const float* __restrict__ Wv, const float* __restrict__ Wqp,
    const float* __restrict__ Wkp, const float* __restrict__ Wvp,
    float* __restrict__ ws)
{
  __shared__ __align__(16) float A_s[PJ_BM][PJ_AP];   // 49664 B
  __shared__ __align__(16) float B_s[PJ_BK][PJ_BN];   //  8192 B

  const int t  = threadIdx.x;
  const int rb = blockIdx.x / 18;          // 0..15 row tile
  const int cb = blockIdx.x % 18;          // 0..17 col tile
  const int tc = t & 15, tr = t >> 4;      // micro-tile coords

  #pragma unroll
  for (int j = 0; j < 12; ++j) {
    int idx = t + j*256;
    int row = idx / 96, kq = idx % 96;
    float4 v4 = *(const float4*)(S + (size_t)(rb*PJ_BM + row)*CSZ + kq*4);
    *(float4*)&A_s[row][kq*4] = v4;
  }

  const float* Wp[2]; int ncB[2], lcB[2], kkB[2], cqB[2];
  #pragma unroll
  for (int j = 0; j < 2; ++j) {
    int idx = t + j*256;
    int kk = idx >> 4, cq = idx & 15;
    kkB[j] = kk; cqB[j] = cq;
    int col = cb*PJ_BN + cq*4;
    if      (col < 192) { Wp[j]=Wq;  ncB[j]=192; lcB[j]=col;     }
    else if (col < 384) { Wp[j]=Wk;  ncB[j]=192; lcB[j]=col-192; }
    else if (col < 576) { Wp[j]=Wv;  ncB[j]=192; lcB[j]=col-384; }
    else if (col < 720) { Wp[j]=Wqp; ncB[j]=144; lcB[j]=col-576; }
    else if (col < 864) { Wp[j]=Wkp; ncB[j]=144; lcB[j]=col-720; }
    else                { Wp[j]=Wvp; ncB[j]=288; lcB[j]=col-864; }
  }

  float4 bw[2];
  #pragma unroll
  for (int j = 0; j < 2; ++j)
    bw[j] = *(const float4*)(Wp[j] + (size_t)kkB[j]*ncB[j] + lcB[j]);

  float acc[2][4];
  #pragma unroll
  for (int i=0;i<2;i++)
    #pragma unroll
    for (int jj=0;jj<4;jj++) acc[i][jj]=0.f;

  for (int ki = 0; ki < PJ_NK; ++ki) {
    __syncthreads();
    #pragma unroll
    for (int j = 0; j < 2; ++j)
      *(float4*)&B_s[kkB[j]][cqB[j]*4] = bw[j];
    __syncthreads();

    if (ki + 1 < PJ_NK) {
      #pragma unroll
      for (int j = 0; j < 2; ++j)
        bw[j] = *(const float4*)(Wp[j] + (size_t)((ki+1)*PJ_BK + kkB[j])*ncB[j] + lcB[j]);
    }

    #pragma unroll
    for (int kk4 = 0; kk4 < PJ_BK/4; ++kk4) {
      float4 a0 = *(const float4*)&A_s[tr*2+0][ki*PJ_BK + kk4*4];
      float4 a1 = *(const float4*)&A_s[tr*2+1][ki*PJ_BK + kk4*4];
      const float* a0p = (const float*)&a0;
      const float* a1p = (const float*)&a1;
      #pragma unroll
      for (int e = 0; e < 4; ++e) {
        float4 b4 = *(const float4*)&B_s[kk4*4+e][tc*4];
        float f0 = a0p[e], f1 = a1p[e];
        acc[0][0] += f0*b4.x; acc[0][1] += f0*b4.y; acc[0][2] += f0*b4.z; acc[0][3] += f0*b4.w;
        acc[1][0] += f1*b4.x; acc[1][1] += f1*b4.y; acc[1][2] += f1*b4.z; acc[1][3] += f1*b4.w;
      }
    }
  }

  {
    int col = cb*PJ_BN + tc*4;
    float* dst; int stride; int lcc;
    if      (col < 192) { dst = ws+OFF_Q;   stride=192; lcc=col;     }
    else if (col < 384) { dst = ws+OFF_K;   stride=192; lcc=col-192; }
    else if (col < 576) { dst = ws+OFF_V;   stride=192; lcc=col-384; }
    else if (col < 720) { dst = ws+OFF_LQ;  stride=144; lcc=col-576; }
    else if (col < 864) { dst = ws+OFF_LK;  stride=144; lcc=col-720; }
    else                { dst = ws+OFF_LVP; stride=288; lcc=col-864; }
    #pragma unroll
    for (int i = 0; i < 2; ++i) {
      int row = rb*PJ_BM + tr*2 + i;
      *(float4*)&dst[(size_t)row*stride + lcc] =
          make_float4(acc[i][0], acc[i][1], acc[i][2], acc[i][3]);
    }
  }
}

// ---------------------------------------------------------------------------
// Kernel 1b: apply rigid frames in place to qp, kp, vp -> lq, lk, lvp
// ---------------------------------------------------------------------------
__global__ __launch_bounds__(256) void k_frames(
    const float* __restrict__ rot, const float* __restrict__ trans,
    float* __restrict__ ws)
{
  int gid = blockIdx.x*256 + threadIdx.x;
  if (gid >= NRES*192) return;
  int m = gid / 192;
  int rest = gid % 192;
  float* base; int pidx;
  if      (rest <  48) { base = ws + OFF_LQ  + (size_t)m*HPQ3; pidx = rest;     }
  else if (rest <  96) { base = ws + OFF_LK  + (size_t)m*HPQ3; pidx = rest-48;  }
  else                 { base = ws + OFF_LVP + (size_t)m*HPV3; pidx = rest-96;  }
  float x = base[pidx*3+0], y = base[pidx*3+1], z = base[pidx*3+2];
  const float* R = rot + (size_t)m*9;
  const float* T = trans + (size_t)m*3;
  float o0 = R[0]*x + R[1]*y + R[2]*z + T[0];
  float o1 = R[3]*x + R[4]*y + R[5]*z + T[1];
  float o2 = R[6]*x + R[7]*y + R[8]*z + T[2];
  base[pidx*3+0]=o0; base[pidx*3+1]=o1; base[pidx*3+2]=o2;
}

// ---------------------------------------------------------------------------
// Kernel 1c: build khat[h][m][32] and qhat[h][n][32] (correctness-proven).
//   qhat = [SCALE_SINGLE*q, -2*SF*sp*lq, 1, 0,0,0]
//   khat = [k,              lk,          SF*sp*|lk|^2, 0,0,0]
// ---------------------------------------------------------------------------
__global__ __launch_bounds__(256) void k_hat(
    const float* __restrict__ scale_head, float* __restrict__ ws)
{
  const int r = blockIdx.x;
  const int t = threadIdx.x;
  __shared__ float sSp[NH];
  if (t < NH) { float x = scale_head[t];
                sSp[t] = (x > 20.f) ? x : log1pf(__expf(x)); }
  __syncthreads();

  for (int i = t; i < NH*32; i += 256) {
    const int h = i >> 5, j = i & 31;
    const float* kk = ws + OFF_K  + (size_t)r*HC   + h*CC;
    const float* lk = ws + OFF_LK + (size_t)r*HPQ3 + h*12;
    const float* qq = ws + OFF_Q  + (size_t)r*HC   + h*CC;
    const float* lq = ws + OFF_LQ + (size_t)r*HPQ3 + h*12;
    float kv, qv;
    if (j < 16)      { kv = kk[j];    qv = SCALE_SINGLE * qq[j]; }
    else if (j < 28) { kv = lk[j-16]; qv = -2.f*SCALE_FRAME*sSp[h]*lq[j-16]; }
    else if (j == 28) {
      float s2 = 0.f;
      #pragma unroll
      for (int e=0;e<12;e++) { float v = lk[e]; s2 += v*v; }
      kv = SCALE_FRAME * sSp[h] * s2;
      qv = 1.f;
    } else { kv = 0.f; qv = 0.f; }
    ws[OFF_KH + ((size_t)h*NRES + r)*32 + j] = kv;
    ws[OFF_QH + ((size_t)h*NRES + r)*32 + j] = qv;
  }
}

// ---------------------------------------------------------------------------
// Kernel 1d: batched GEMM  wlog[n][h][m] = qhat_h[n,:] . khat_h[m,:]
// ---------------------------------------------------------------------------
#define QK_P 68
__global__ __launch_bounds__(256) void k_qk(float* __restrict__ ws)
{
  __shared__ __align__(16) float Qs[32*QK_P];   // 8704 B
  __shared__ __align__(16) float Ks[32*QK_P];   // 8704 B

  const int bid = blockIdx.x;
  const int h  = bid >> 6;
  const int nt = (bid >> 3) & 7;
  const int mt = bid & 7;
  const int t  = threadIdx.x;
  const int tc = t & 15, tr = t >> 4;

  const float4* qsrc = (const float4*)(ws + OFF_QH + ((size_t)h*NRES + nt*64)*32);
  const float4* ksrc = (const float4*)(ws + OFF_KH + ((size_t)h*NRES + mt*64)*32);

  #pragma unroll
  for (int u = 0; u < 2; ++u) {
    int idx = t + u*256;            // 0..511
    int r = idx >> 3, j4 = idx & 7;
    float4 qv = qsrc[idx];
    float4 kv = ksrc[idx];
    Qs[(j4*4+0)*QK_P + r] = qv.x;
    Qs[(j4*4+1)*QK_P + r] = qv.y;
    Qs[(j4*4+2)*QK_P + r] = qv.z;
    Qs[(j4*4+3)*QK_P + r] = qv.w;
    Ks[(j4*4+0)*QK_P + r] = kv.x;
    Ks[(j4*4+1)*QK_P + r] = kv.y;
    Ks[(j4*4+2)*QK_P + r] = kv.z;
    Ks[(j4*4+3)*QK_P + r] = kv.w;
  }
  __syncthreads();

  float acc[4][4];
  #pragma unroll
  for (int i=0;i<4;i++)
    #pragma unroll
    for (int k2=0;k2<4;k2++) acc[i][k2]=0.f;

  #pragma unroll
  for (int j = 0; j < 32; ++j) {
    float4 qv = *(const float4*)&Qs[j*QK_P + tr*4];
    float4 kv = *(const float4*)&Ks[j*QK_P + tc*4];
    acc[0][0] += qv.x*kv.x; acc[0][1] += qv.x*kv.y; acc[0][2] += qv.x*kv.z; acc[0][3] += qv.x*kv.w;
    acc[1][0] += qv.y*kv.x; acc[1][1] += qv.y*kv.y; acc[1][2] += qv.y*kv.z; acc[1][3] += qv.y*kv.w;
    acc[2][0] += qv.z*kv.x; acc[2][1] += qv.z*kv.y; acc[2][2] += qv.z*kv.z; acc[2][3] += qv.z*kv.w;
    acc[3][0] += qv.w*kv.x; acc[3][1] += qv.w*kv.y; acc[3][2] += qv.w*kv.z; acc[3][3] += qv.w*kv.w;
  }

  float* wlog = ws + OFF_LOG;
  #pragma unroll
  for (int i = 0; i < 4; ++i) {
    int n = nt*64 + tr*4 + i;
    *(float4*)&wlog[((size_t)n*NH + h)*NRES + mt*64 + tc*4] =
        make_float4(acc[i][0], acc[i][1], acc[i][2], acc[i][3]);
  }
}

// ---------------------------------------------------------------------------
// Kernel 2 (PRIMARY): fused attention. Phase A = round-10 measured-best.
// NEW this round: phases C1 and C2 get the same register prefetch-ahead
// pipelining that won in phase A (round 10) — next iteration's global loads
// issued before current iteration's FMAs. No sync/layout changes.
// ---------------------------------------------------------------------------
__global__ __launch_bounds__(512) void k_attn2(
    const float* __restrict__ pair,
    const float* __restrict__ rot, const float* __restrict__ trans,
    const float* __restrict__ Wb,
    float* __restrict__ ws)
{
  const int n = blockIdx.x;
  const int t = threadIdx.x;

  __shared__ __align__(16) float sLogit[NH*LROW];   // 24768 B
  // union: phase A pair-stage [16][ZP] (33024 B) / phase C1 sOP[4][NH*CZ] (24576 B)
  __shared__ __align__(16) float sU[16*ZP];         // 33024 B
  __shared__ __align__(16) float sOL[HPV3];
  __shared__ float sR[9];
  __shared__ float sT[3];

  const float* v    = ws + OFF_V;
  const float* lvp  = ws + OFF_LVP;
  const float* wlog = ws + OFF_LOG;
  float* att = ws + OFF_ATT;

  if (t >= 488 && t < 497)      sR[t-488] = rot[(size_t)n*9 + (t-488)];
  else if (t >= 497 && t < 500) sT[t-497] = trans[(size_t)n*3 + (t-497)];

  // ---------------- Phase A: pipelined staged pair-bias + precomputed qk ---
  {
    float acch[NH];
    #pragma unroll
    for (int h=0;h<NH;h++)
      acch[h] = wlog[((size_t)n*NH + h)*NRES + t];   // coalesced qk term

    const float4* pr4 = (const float4*)(pair + (size_t)n*NRES*CZ);

    // prefetch chunk 0 into registers (addresses: idx = t + j*512)
    float4 c0 = pr4[(size_t)((t +    0) >> 2)*32 + 0*4 + (t & 3)];
    float4 c1 = pr4[(size_t)((t +  512) >> 2)*32 + 0*4 + (t & 3)];
    float4 c2 = pr4[(size_t)((t + 1024) >> 2)*32 + 0*4 + (t & 3)];
    float4 c3 = pr4[(size_t)((t + 1536) >> 2)*32 + 0*4 + (t & 3)];

    #pragma unroll 1
    for (int zc = 0; zc < 8; ++zc) {
      __syncthreads();                    // prev chunk's LDS reads done
      // write staged regs, transposed: sU[zwithin*ZP + row]
      {
#define WR_J(CJ, J)                                                   \
        { int idx = t + (J)*512;                                      \
          int row = idx >> 2, q = idx & 3;                            \
          sU[(q*4+0)*ZP + row] = CJ.x;                                \
          sU[(q*4+1)*ZP + row] = CJ.y;                                \
          sU[(q*4+2)*ZP + row] = CJ.z;                                \
          sU[(q*4+3)*ZP + row] = CJ.w; }
        WR_J(c0, 0) WR_J(c1, 1) WR_J(c2, 2) WR_J(c3, 3)
#undef WR_J
      }
      // prefetch next chunk (latency hidden under compute below)
      if (zc < 7) {
        c0 = pr4[(size_t)((t +    0) >> 2)*32 + (zc+1)*4 + (t & 3)];
        c1 = pr4[(size_t)((t +  512) >> 2)*32 + (zc+1)*4 + (t & 3)];
        c2 = pr4[(size_t)((t + 1024) >> 2)*32 + (zc+1)*4 + (t & 3)];
        c3 = pr4[(size_t)((t + 1536) >> 2)*32 + (zc+1)*4 + (t & 3)];
      }
      __syncthreads();
      // compute: z wave-uniform -> Wb via s_load; LDS reads lane-consecutive
      #pragma unroll
      for (int e = 0; e < 16; ++e) {
        float pv = sU[e*ZP + t];
        const float* wrow = Wb + (size_t)(zc*16 + e)*NH;
        #pragma unroll
        for (int h=0;h<NH;h++) acch[h] += pv * wrow[h];
      }
    }
    #pragma unroll
    for (int h=0;h<NH;h++) sLogit[h*LROW + t] = acch[h];
  }
  __syncthreads();

  // ---------------- Phase B: softmax over m, wave per head -----------------
  {
    int wave = t >> 6, lane = t & 63;
    for (int h = wave; h < NH; h += 8) {
      float x[8]; float mx = -1e30f;
      #pragma unroll
      for (int j=0;j<8;j++) { x[j] = sLogit[h*LROW + lane + j*64]; mx = fmaxf(mx, x[j]); }
      #pragma unroll
      for (int d=1; d<64; d<<=1) mx = fmaxf(mx, __shfl_xor(mx, d, 64));
      float s = 0.f;
      #pragma unroll
      for (int j=0;j<8;j++) { x[j] = __expf(x[j]-mx); s += x[j]; }
      #pragma unroll
      for (int d=1; d<64; d<<=1) s += __shfl_xor(s, d, 64);
      float inv = 1.f/s;
      #pragma unroll
      for (int j=0;j<8;j++) sLogit[h*LROW + lane + j*64] = x[j]*inv;
    }
  }
  __syncthreads();

  // ---------------- Phase C1: o_pair, register-pipelined (r10 pattern) -----
  {
    const int zq = t & 31;
    const int hg = (t >> 5) & 3;
    const int mg = t >> 7;
    float a0[4] = {0,0,0,0}, a1[4] = {0,0,0,0}, a2[4] = {0,0,0,0};
    const float* pb = pair + (size_t)n*NRES*CZ + zq*4;

    float4 pc0 = *(const float4*)(pb + (size_t)(mg*128 + 0)*CZ);
    float4 pc1 = *(const float4*)(pb + (size_t)(mg*128 + 1)*CZ);
    float4 pc2 = *(const float4*)(pb + (size_t)(mg*128 + 2)*CZ);
    float4 pc3 = *(const float4*)(pb + (size_t)(mg*128 + 3)*CZ);

#define C1_FMA(M0)                                                        \
    {                                                                     \
      float4 w0 = *(const float4*)&sLogit[(hg+0)*LROW + (M0)];            \
      float4 w1 = *(const float4*)&sLogit[(hg+4)*LROW + (M0)];            \
      float4 w2 = *(const float4*)&sLogit[(hg+8)*LROW + (M0)];            \
      const float* w0p = (const float*)&w0;                               \
      const float* w1p = (const float*)&w1;                               \
      const float* w2p = (const float*)&w2;                               \
      const float* q0 = (const float*)&pc0;                               \
      const float* q1 = (const float*)&pc1;                               \
      const float* q2 = (const float*)&pc2;                               \
      const float* q3 = (const float*)&pc3;                               \
      _Pragma("unroll")                                                   \
      for (int e=0;e<4;e++) {                                             \
        a0[e] += w0p[0]*q0[e] + w0p[1]*q1[e] + w0p[2]*q2[e] + w0p[3]*q3[e]; \
        a1[e] += w1p[0]*q0[e] + w1p[1]*q1[e] + w1p[2]*q2[e] + w1p[3]*q3[e]; \
        a2[e] += w2p[0]*q0[e] + w2p[1]*q1[e] + w2p[2]*q2[e] + w2p[3]*q3[e]; \
      }                                                                   \
    }

    for (int mb = 0; mb < 31; ++mb) {
      int m0 = mg*128 + mb*4;
      float4 pn0 = *(const float4*)(pb + (size_t)(m0+4)*CZ);
      float4 pn1 = *(const float4*)(pb + (size_t)(m0+5)*CZ);
      float4 pn2 = *(const float4*)(pb + (size_t)(m0+6)*CZ);
      float4 pn3 = *(const float4*)(pb + (size_t)(m0+7)*CZ);
      C1_FMA(m0)
      pc0 = pn0; pc1 = pn1; pc2 = pn2; pc3 = pn3;
    }
    C1_FMA(mg*128 + 31*4)
#undef C1_FMA

    // sOP lives in sU: sOP[mg][idx] = sU[mg*(NH*CZ) + idx]
    *(float4*)&sU[mg*(NH*CZ) + (hg+0)*CZ + zq*4] = make_float4(a0[0],a0[1],a0[2],a0[3]);
    *(float4*)&sU[mg*(NH*CZ) + (hg+4)*CZ + zq*4] = make_float4(a1[0],a1[1],a1[2],a1[3]);
    *(float4*)&sU[mg*(NH*CZ) + (hg+8)*CZ + zq*4] = make_float4(a2[0],a2[1],a2[2],a2[3]);
  }

  // ---------------- Phase C2: o_single / o_local, register-pipelined -------
  {
    if (t < 480) {
      float acc = 0.f;
      const float* src; int stride; int off; int h;
      if (t < 192) { h = t >> 4;        src = v;   stride = HC;   off = t;      }
      else         { int idx = t - 192; h = idx/24; src = lvp; stride = HPV3; off = idx; }
      const float* wrow = sLogit + h*LROW;

      float s0 = src[(size_t)0*stride + off];
      float s1 = src[(size_t)1*stride + off];
      float s2 = src[(size_t)2*stride + off];
      float s3 = src[(size_t)3*stride + off];
      for (int m0 = 0; m0 < NRES-4; m0 += 4) {
        float n0 = src[(size_t)(m0+4)*stride + off];
        float n1 = src[(size_t)(m0+5)*stride + off];
        float n2 = src[(size_t)(m0+6)*stride + off];
        float n3 = src[(size_t)(m0+7)*stride + off];
        float4 w4 = *(const float4*)&wrow[m0];
        acc += w4.x*s0 + w4.y*s1 + w4.z*s2 + w4.w*s3;
        s0 = n0; s1 = n1; s2 = n2; s3 = n3;
      }
      {
        float4 w4 = *(const float4*)&wrow[NRES-4];
        acc += w4.x*s0 + w4.y*s1 + w4.z*s2 + w4.w*s3;
      }

      if (t < 192) {
        int h2 = t >> 4;
        att[(size_t)n*ATTD + h2*176 + (t & 15)] = acc;
      } else {
        sOL[t-192] = acc;
      }
    }
  }
  __syncthreads();

  for (int o = t; o < NH*CZ; o += 512) {
    float sres = sU[0*(NH*CZ) + o] + sU[1*(NH*CZ) + o]
               + sU[2*(NH*CZ) + o] + sU[3*(NH*CZ) + o];
    int h = o >> 7, z = o & 127;
    att[(size_t)n*ATTD + h*176 + 16 + z] = sres;
  }

  if (t < 96) {
    int h = t / 8, p = t % 8;
    float x = sOL[h*24 + p*3 + 0] - sT[0];
    float y = sOL[h*24 + p*3 + 1] - sT[1];
    float z = sOL[h*24 + p*3 + 2] - sT[2];
    float o0 = sR[0]*x + sR[3]*y + sR[6]*z;
    float o1 = sR[1]*x + sR[4]*y + sR[7]*z;
    float o2 = sR[2]*x + sR[5]*y + sR[8]*z;
    float nm = sqrtf(o0*o0 + o1*o1 + o2*o2);
    float* ab = att + (size_t)n*ATTD + h*176;
    ab[144 + p*3 + 0] = o0;
    ab[144 + p*3 + 1] = o1;
    ab[144 + p*3 + 2] = o2;
    ab[168 + p] = nm;
  }
}

// ---------------------------------------------------------------------------
// Kernel 2 (FALLBACK: round-0 fused path, used only if ws too small)
// ---------------------------------------------------------------------------
__global__ __launch_bounds__(512) void k_attn(
    const float* __restrict__ pair,
    const float* __restrict__ rot, const float* __restrict__ trans,
    const float* __restrict__ Wb, const float* __restrict__ scale_head,
    float* __restrict__ ws)
{
  const int n = blockIdx.x;
  const int t = threadIdx.x;

  __shared__ __align__(16) float sLogit[NH*LROW];
  __shared__ __align__(16) float sOP[4][NH*CZ];
  __shared__ __align__(16) float sQ[HC];
  __shared__ __align__(16) float sLQ[HPQ3];
  __shared__ float sSp[NH];
  __shared__ __align__(16) float sOL[HPV3];
  __shared__ float sR[9];
  __shared__ float sT[3];

  const float* q   = ws + OFF_Q;
  const float* k   = ws + OFF_K;
  const float* v   = ws + OFF_V;
  const float* lq  = ws + OFF_LQ;
  const float* lk  = ws + OFF_LK;
  const float* lvp = ws + OFF_LVP;
  float* att = ws + OFF_ATT;

  if (t < 192)               sQ[t]      = q[(size_t)n*HC + t];
  else if (t < 336)          sLQ[t-192] = lq[(size_t)n*HPQ3 + (t-192)];
  else if (t < 348) { float x = scale_head[t-336];
                      sSp[t-336] = (x > 20.f) ? x : log1pf(__expf(x)); }
  else if (t < 357)          sR[t-348]  = rot[(size_t)n*9 + (t-348)];
  else if (t < 360)          sT[t-357]  = trans[(size_t)n*3 + (t-357)];
  __syncthreads();

  {
    const int m = t;
    float acch[NH];
    #pragma unroll
    for (int h=0;h<NH;h++) acch[h]=0.f;

    const float4* pr = (const float4*)(pair + ((size_t)n*NRES + m)*CZ);
    for (int zq = 0; zq < CZ/4; ++zq) {
      float4 p4 = pr[zq];
      const float* pp = (const float*)&p4;
      #pragma unroll
      for (int e=0;e<4;e++) {
        float pv_ = pp[e];
        const float* wrow = Wb + (size_t)(zq*4+e)*NH;
        #pragma unroll
        for (int h=0;h<NH;h++) acch[h] += pv_ * wrow[h];
      }
    }

    #pragma unroll
    for (int h=0;h<NH;h++) {
      const float4* kr = (const float4*)(k + (size_t)m*HC + h*CC);
      const float* qrow = sQ + h*CC;
      float d = 0.f;
      #pragma unroll
      for (int j=0;j<4;j++) {
        float4 k4 = kr[j];
        d += k4.x*qrow[j*4+0] + k4.y*qrow[j*4+1] + k4.z*qrow[j*4+2] + k4.w*qrow[j*4+3];
      }
      acch[h] += SCALE_SINGLE * d;

      const float* lkr = lk + (size_t)m*HPQ3 + h*12;
      const float* lqr = sLQ + h*12;
      float d2 = 0.f;
      #pragma unroll
      for (int j=0;j<12;j++) { float df = lqr[j]-lkr[j]; d2 += df*df; }
      acch[h] += SCALE_FRAME * sSp[h] * d2;

      sLogit[h*LROW + m] = acch[h];
    }
  }
  __syncthreads();

  {
    int wave = t >> 6, lane = t & 63;
    for (int h = wave; h < NH; h += 8) {
      float x[8]; float mx = -1e30f;
      #pragma unroll
      for (int j=0;j<8;j++) { x[j] = sLogit[h*LROW + lane + j*64]; mx = fmaxf(mx, x[j]); }
      #pragma unroll
      for (int d=1; d<64; d<<=1) mx = fmaxf(mx, __shfl_xor(mx, d, 64));
      float s = 0.f;
      #pragma unroll
      for (int j=0;j<8;j++) { x[j] = __expf(x[j]-mx); s += x[j]; }
      #pragma unroll
      for (int d=1; d<64; d<<=1) s += __shfl_xor(s, d, 64);
      float inv = 1.f/s;
      #pragma unroll
      for (int j=0;j<8;j++) sLogit[h*LROW + lane + j*64] = x[j]*inv;
    }
  }
  __syncthreads();

  {
    const int zq = t & 31;
    const int hg = (t >> 5) & 3;
    const int mg = t >> 7;
    float a0[4] = {0,0,0,0}, a1[4] = {0,0,0,0}, a2[4] = {0,0,0,0};
    const float* pb = pair + (size_t)n*NRES*CZ + zq*4;
    for (int mb = 0; mb < 32; ++mb) {
      int m0 = mg*128 + mb*4;
      float4 w0 = *(const float4*)&sLogit[(hg+0)*LROW + m0];
      float4 w1 = *(const float4*)&sLogit[(hg+4)*LROW + m0];
      float4 w2 = *(const float4*)&sLogit[(hg+8)*LROW + m0];
      const float* w0p = (const float*)&w0;
      const float* w1p = (const float*)&w1;
      const float* w2p = (const float*)&w2;
      #pragma unroll
      for (int i=0;i<4;i++) {
        float4 p4 = *(const float4*)(pb + (size_t)(m0+i)*CZ);
        const float* pp = (const float*)&p4;
        float f0 = w0p[i], f1 = w1p[i], f2 = w2p[i];
        #pragma unroll
        for (int e=0;e<4;e++) {
          a0[e] += f0*pp[e]; a1[e] += f1*pp[e]; a2[e] += f2*pp[e];
        }
      }
    }
    *(float4*)&sOP[mg][(hg+0)*CZ + zq*4] = make_float4(a0[0],a0[1],a0[2],a0[3]);
    *(float4*)&sOP[mg][(hg+4)*CZ + zq*4] = make_float4(a1[0],a1[1],a1[2],a1[3]);
    *(float4*)&sOP[mg][(hg+8)*CZ + zq*4] = make_float4(a2[0],a2[1],a2[2],a2[3]);
  }

  {
    if (t < 480) {
      float acc = 0.f;
      const float* src; int stride; int off; int h;
      if (t < 192) { h = t >> 4;        src = v;   stride = HC;   off = t;      }
      else         { int idx = t - 192; h = idx/24; src = lvp; stride = HPV3; off = idx; }
      const float* wrow = sLogit + h*LROW;
      for (int m0 = 0; m0 < NRES; m0 += 4) {
        float4 w4 = *(const float4*)&wrow[m0];
        acc += w4.x * src[(size_t)(m0+0)*stride + off];
        acc += w4.y * src[(size_t)(m0+1)*stride + off];
        acc += w4.z * src[(size_t)(m0+2)*stride + off];
        acc += w4.w * src[(size_t)(m0+3)*stride + off];
      }
      if (t < 192) {
        int h2 = t >> 4;
        att[(size_t)n*ATTD + h2*176 + (t & 15)] = acc;
      } else {
        sOL[t-192] = acc;
      }
    }
  }
  __syncthreads();

  for (int o = t; o < NH*CZ; o += 512) {
    float sres = sOP[0][o] + sOP[1][o] + sOP[2][o] + sOP[3][o];
    int h = o >> 7, z = o & 127;
    att[(size_t)n*ATTD + h*176 + 16 + z] = sres;
  }

  if (t < 96) {
    int h = t / 8, p = t % 8;
    float x = sOL[h*24 + p*3 + 0] - sT[0];
    float y = sOL[h*24 + p*3 + 1] - sT[1];
    float z = sOL[h*24 + p*3 + 2] - sT[2];
    float o0 = sR[0]*x + sR[3]*y + sR[6]*z;
    float o1 = sR[1]*x + sR[4]*y + sR[7]*z;
    float o2 = sR[2]*x + sR[5]*y + sR[8]*z;
    float nm = sqrtf(o0*o0 + o1*o1 + o2*o2);
    float* ab = att + (size_t)n*ATTD + h*176;
    ab[144 + p*3 + 0] = o0;
    ab[144 + p*3 + 1] = o1;
    ab[144 + p*3 + 2] = o2;
    ab[168 + p] = nm;
  }
}

// ---------------------------------------------------------------------------
// Kernel 3: out = att[512,2112] @ Wout[2112,384], K-split tiled GEMM.
// ---------------------------------------------------------------------------
#define KOUT_BK 24

__global__ __launch_bounds__(256) void k_out_part(
    const float* __restrict__ ws, const float* __restrict__ Wout,
    float* __restrict__ part, int KS)
{
  const float* att = ws + OFF_ATT;
  const int bid  = blockIdx.x;
  const int ks   = bid / 48;
  const int tile = bid % 48;
  const int rb   = tile / 6, cb = tile % 6;
  const int KLEN = ATTD / KS;
  const int k0b  = ks * KLEN;

  __shared__ __align__(16) float A_s[64][KOUT_BK+1];
  __shared__ __align__(16) float B_s[KOUT_BK][64];

  const int t  = threadIdx.x;
  const int tc = t & 15, tr = t >> 4;

  float acc[4][4];
  #pragma unroll
  for (int i=0;i<4;i++)
    #pragma unroll
    for (int j=0;j<4;j++) acc[i][j]=0.f;

  for (int k0 = k0b; k0 < k0b + KLEN; k0 += KOUT_BK) {
    __syncthreads();
    #pragma unroll
    for (int j = 0; j < 6; ++j) {
      int idx = t + j*256;
      int r  = idx / KOUT_BK, kk = idx % KOUT_BK;
      A_s[r][kk] = att[(size_t)(rb*64 + r)*ATTD + k0 + kk];
      int kk2 = idx >> 6, c = idx & 63;
      B_s[kk2][c] = Wout[(size_t)(k0 + kk2)*CSZ + cb*64 + c];
    }
    __syncthreads();
    #pragma unroll
    for (int kk = 0; kk < KOUT_BK; ++kk) {
      float4 b4 = *(const float4*)&B_s[kk][tc*4];
      float a0 = A_s[tr*4+0][kk];
      float a1 = A_s[tr*4+1][kk];
      float a2 = A_s[tr*4+2][kk];
      float a3 = A_s[tr*4+3][kk];
      acc[0][0] += a0*b4.x; acc[0][1] += a0*b4.y; acc[0][2] += a0*b4.z; acc[0][3] += a0*b4.w;
      acc[1][0] += a1*b4.x; acc[1][1] += a1*b4.y; acc[1][2] += a1*b4.z; acc[1][3] += a1*b4.w;
      acc[2][0] += a2*b4.x; acc[2][1] += a2*b4.y; acc[2][2] += a2*b4.z; acc[2][3] += a2*b4.w;
      acc[3][0] += a3*b4.x; acc[3][1] += a3*b4.y; acc[3][2] += a3*b4.z; acc[3][3] += a3*b4.w;
    }
  }

  float* pb = part + (size_t)ks*NRES*CSZ;
  #pragma unroll
  for (int i=0;i<4;i++) {
    int row = rb*64 + tr*4 + i;
    int col = cb*64 + tc*4;
    *(float4*)&pb[(size_t)row*CSZ + col] =
        make_float4(acc[i][0], acc[i][1], acc[i][2], acc[i][3]);
  }
}

__global__ __launch_bounds__(256) void k_out_reduce(
    const float* __restrict__ part, const float* __restrict__ bout,
    float* __restrict__ out, int KS)
{
  int idx4 = blockIdx.x*256 + threadIdx.x;
  if (idx4 >= NRES*CSZ/4) return;
  int c4 = idx4 % (CSZ/4);
  float4 s = ((const float4*)bout)[c4];
  const float4* p4 = (const float4*)part;
  for (int ks = 0; ks < KS; ++ks) {
    float4 v = p4[(size_t)ks*(NRES*CSZ/4) + idx4];
    s.x += v.x; s.y += v.y; s.z += v.z; s.w += v.w;
  }
  ((float4*)out)[idx4] = s;
}

__global__ __launch_bounds__(256) void k_out_v1(
    const float* __restrict__ ws, const float* __restrict__ Wout,
    const float* __restrict__ bout, float* __restrict__ out)
{
  const float* att = ws + OFF_ATT;
  int cb = blockIdx.x % 6;
  int rb = blockIdx.x / 6;
  int t  = threadIdx.x;
  int c  = cb*64 + (t & 63);
  int rg = t >> 6;
  int r0 = rb*16;
  float acc[4] = {0.f,0.f,0.f,0.f};
  for (int a = 0; a < ATTD; ++a) {
    float wv = Wout[(size_t)a*CSZ + c];
    #pragma unroll
    for (int i=0;i<4;i++)
      acc[i] += att[(size_t)(r0 + rg + 4*i)*ATTD + a] * wv;
  }
  float b = bout[c];
  #pragma unroll
  for (int i=0;i<4;i++)
    out[(size_t)(r0 + rg + 4*i)*CSZ + c] = acc[i] + b;
}

// ---------------------------------------------------------------------------
extern "C" void kernel_launch(void* const* d_in, const int* in_sizes, int n_in,
                              void* d_out, int out_size, void* d_ws, size_t ws_size,
                              hipStream_t stream) {
  const float* S     = (const float*)d_in[0];
  const float* pair  = (const float*)d_in[1];
  const float* rot   = (const float*)d_in[2];
  const float* trans = (const float*)d_in[3];
  const float* Wq    = (const float*)d_in[4];
  const float* Wk    = (const float*)d_in[5];
  const float* Wv    = (const float*)d_in[6];
  const float* Wqp   = (const float*)d_in[7];
  const float* Wkp   = (const float*)d_in[8];
  const float* Wvp   = (const float*)d_in[9];
  const float* Wb    = (const float*)d_in[10];
  const float* Wout  = (const float*)d_in[11];
  const float* bout  = (const float*)d_in[12];
  const float* sh    = (const float*)d_in[13];
  float* out = (float*)d_out;
  float* ws  = (float*)d_ws;

  hipLaunchKernelGGL(k_proj2,  dim3(16*18), dim3(256), 0, stream,
                     S, Wq, Wk, Wv, Wqp, Wkp, Wvp, ws);
  hipLaunchKernelGGL(k_frames, dim3((NRES*192+255)/256), dim3(256), 0, stream,
                     rot, trans, ws);

  const size_t need_new = (size_t)(OFF_LOG + LOG_FLOATS) * sizeof(float);
  if (ws_size >= need_new) {
    hipLaunchKernelGGL(k_hat,   dim3(NRES), dim3(256), 0, stream, sh, ws);
    hipLaunchKernelGGL(k_qk,    dim3(NH*64), dim3(256), 0, stream, ws);
    hipLaunchKernelGGL(k_attn2, dim3(NRES), dim3(512), 0, stream,
                       pair, rot, trans, Wb, ws);
  } else {
    hipLaunchKernelGGL(k_attn,  dim3(NRES), dim3(512), 0, stream,
                       pair, rot, trans, Wb, sh, ws);
  }

  int KS = 0;
  const int cands[4] = {8, 4, 2, 1};
  for (int i = 0; i < 4; ++i) {
    size_t need = ((size_t)OFF_PART + (size_t)cands[i]*NRES*CSZ) * sizeof(float);
    if (need <= ws_size) { KS = cands[i]; break; }
  }
  if (KS > 0) {
    hipLaunchKernelGGL(k_out_part, dim3(48*KS), dim3(256), 0, stream,
                       ws, Wout, ws + OFF_PART, KS);
    hipLaunchKernelGGL(k_out_reduce, dim3((NRES*CSZ/4 + 255)/256), dim3(256), 0, stream,
                       ws + OFF_PART, bout, out, KS);
  } else {
    hipLaunchKernelGGL(k_out_v1, dim3(32*6), dim3(256), 0, stream,
                       ws, Wout, bout, out);
  }
}

// Round 15
// 139.457 us; speedup vs baseline: 1.4747x; 1.0209x over previous
//
#include <hip/hip_runtime.h>
#include <math.h>

// Problem constants
#define NRES 512
#define CSZ  384
#define CZ   128
#define CC   16
#define PQ   4
#define PV   8
#define NH   12

#define HC    (NH*CC)        // 192
#define HPQ3  (NH*PQ*3)      // 144
#define HPV3  (NH*PV*3)      // 288
#define ATTD  (NH*(CZ+CC+PV*4)) // 2112

// workspace layout (floats)
#define OFF_Q   0
#define OFF_K   (OFF_Q  + NRES*HC)     // 98304
#define OFF_V   (OFF_K  + NRES*HC)     // 196608
#define OFF_LQ  (OFF_V  + NRES*HC)     // 294912
#define OFF_LK  (OFF_LQ + NRES*HPQ3)   // 368640
#define OFF_LVP (OFF_LK + NRES*HPQ3)   // 442368
#define OFF_ATT (OFF_LVP+ NRES*HPV3)   // 589824  (512*2112 = 1081344 floats)
#define OFF_LOG (OFF_ATT + NRES*ATTD)  // 1671168: qk-logits [512][12][512]
// partials for the output GEMM reuse the logits region (dead by then)
#define OFF_PART OFF_LOG
#define LOG_FLOATS (NRES*NH*NRES)      // 3145728

// khat/qhat scratch lives in the (not yet written) ATT region:
#define OFF_KH  OFF_ATT
#define OFF_QH  (OFF_ATT + NH*NRES*32)   // +196608

#define SCALE_SINGLE 0.25f
#define SCALE_FRAME  (-0.1178511301977579f)  // -1/sqrt(72)

#define LROW 516   // padded logit row
#define ZP   516   // transposed pair-stage stride (2-way bank alias = free)

// ---------------------------------------------------------------------------
// Kernel 1: projection GEMM  C[512,1152] = S[512,384] @ Wcat[384,1152]
// ---------------------------------------------------------------------------
#define PJ_BM 32
#define PJ_BN 64
#define PJ_BK 32
#define PJ_NK (CSZ/PJ_BK)   // 12
#define PJ_AP 388           // padded A row (floats), mult of 4

__global__ __launch_bounds__(256) void k_proj2(
    const float* __restrict__ S,
    const float* __restrict__ Wq, const float* __restrict__ Wk,
    const float* __restrict__ Wv, const float* __restrict__ Wqp,
    const float* __restrict__ Wkp, const float* __restrict__ Wvp,
    float* __restrict__ ws)
{
  __shared__ __align__(16) float A_s[PJ_BM][PJ_AP];   // 49664 B
  __shared__ __align__(16) float B_s[PJ_BK][PJ_BN];   //  8192 B

  const int t  = threadIdx.x;
  const int rb = blockIdx.x / 18;          // 0..15 row tile
  const int cb = blockIdx.x % 18;          // 0..17 col tile
  const int tc = t & 15, tr = t >> 4;      // micro-tile coords

  #pragma unroll
  for (int j = 0; j < 12; ++j) {
    int idx = t + j*256;
    int row = idx / 96, kq = idx % 96;
    float4 v4 = *(const float4*)(S + (size_t)(rb*PJ_BM + row)*CSZ + kq*4);
    *(float4*)&A_s[row][kq*4] = v4;
  }

  const float* Wp[2]; int ncB[2], lcB[2], kkB[2], cqB[2];
  #pragma unroll
  for (int j = 0; j < 2; ++j) {
    int idx = t + j*256;
    int kk = idx >> 4, cq = idx & 15;
    kkB[j] = kk; cqB[j] = cq;
    int col = cb*PJ_BN + cq*4;
    if      (col < 192) { Wp[j]=Wq;  ncB[j]=192; lcB[j]=col;     }
    else if (col < 384) { Wp[j]=Wk;  ncB[j]=192; lcB[j]=col-192; }
    else if (col < 576) { Wp[j]=Wv;  ncB[j]=192; lcB[j]=col-384; }
    else if (col < 720) { Wp[j]=Wqp; ncB[j]=144; lcB[j]=col-576; }
    else if (col < 864) { Wp[j]=Wkp; ncB[j]=144; lcB[j]=col-720; }
    else                { Wp[j]=Wvp; ncB[j]=288; lcB[j]=col-864; }
  }

  float4 bw[2];
  #pragma unroll
  for (int j = 0; j < 2; ++j)
    bw[j] = *(const float4*)(Wp[j] + (size_t)kkB[j]*ncB[j] + lcB[j]);

  float acc[2][4];
  #pragma unroll
  for (int i=0;i<2;i++)
    #pragma unroll
    for (int jj=0;jj<4;jj++) acc[i][jj]=0.f;

  for (int ki = 0; ki < PJ_NK; ++ki) {
    __syncthreads();
    #pragma unroll
    for (int j = 0; j < 2; ++j)
      *(float4*)&B_s[kkB[j]][cqB[j]*4] = bw[j];
    __syncthreads();

    if (ki + 1 < PJ_NK) {
      #pragma unroll
      for (int j = 0; j < 2; ++j)
        bw[j] = *(const float4*)(Wp[j] + (size_t)((ki+1)*PJ_BK + kkB[j])*ncB[j] + lcB[j]);
    }

    #pragma unroll
    for (int kk4 = 0; kk4 < PJ_BK/4; ++kk4) {
      float4 a0 = *(const float4*)&A_s[tr*2+0][ki*PJ_BK + kk4*4];
      float4 a1 = *(const float4*)&A_s[tr*2+1][ki*PJ_BK + kk4*4];
      const float* a0p = (const float*)&a0;
      const float* a1p = (const float*)&a1;
      #pragma unroll
      for (int e = 0; e < 4; ++e) {
        float4 b4 = *(const float4*)&B_s[kk4*4+e][tc*4];
        float f0 = a0p[e], f1 = a1p[e];
        acc[0][0] += f0*b4.x; acc[0][1] += f0*b4.y; acc[0][2] += f0*b4.z; acc[0][3] += f0*b4.w;
        acc[1][0] += f1*b4.x; acc[1][1] += f1*b4.y; acc[1][2] += f1*b4.z; acc[1][3] += f1*b4.w;
      }
    }
  }

  {
    int col = cb*PJ_BN + tc*4;
    float* dst; int stride; int lcc;
    if      (col < 192) { dst = ws+OFF_Q;   stride=192; lcc=col;     }
    else if (col < 384) { dst = ws+OFF_K;   stride=192; lcc=col-192; }
    else if (col < 576) { dst = ws+OFF_V;   stride=192; lcc=col-384; }
    else if (col < 720) { dst = ws+OFF_LQ;  stride=144; lcc=col-576; }
    else if (col < 864) { dst = ws+OFF_LK;  stride=144; lcc=col-720; }
    else                { dst = ws+OFF_LVP; stride=288; lcc=col-864; }
    #pragma unroll
    for (int i = 0; i < 2; ++i) {
      int row = rb*PJ_BM + tr*2 + i;
      *(float4*)&dst[(size_t)row*stride + lcc] =
          make_float4(acc[i][0], acc[i][1], acc[i][2], acc[i][3]);
    }
  }
}

// ---------------------------------------------------------------------------
// Kernel 1b (FUSED): frames + khat/qhat for one residue per block.
// Phase 1 applies rigid frames to qp/kp/vp (lq/lk kept in LDS too);
// phase 2 emits khat[h][r][32], qhat[h][r][32]. Saves a launch + lq/lk
// global round-trip vs separate k_frames/k_hat. Hat phase is harmless in
// the fallback path (ATT region fully overwritten by k_attn later).
// ---------------------------------------------------------------------------
__global__ __launch_bounds__(256) void k_frames_hat(
    const float* __restrict__ rot, const float* __restrict__ trans,
    const float* __restrict__ scale_head, float* __restrict__ ws)
{
  const int r = blockIdx.x;
  const int t = threadIdx.x;
  __shared__ float sSp[NH];
  __shared__ __align__(16) float sLQ[HPQ3];
  __shared__ __align__(16) float sLK[HPQ3];
  __shared__ float sR[9];
  __shared__ float sT[3];

  if (t < NH) { float x = scale_head[t];
                sSp[t] = (x > 20.f) ? x : log1pf(__expf(x)); }
  else if (t >= 16 && t < 25) sR[t-16] = rot[(size_t)r*9 + (t-16)];
  else if (t >= 25 && t < 28) sT[t-25] = trans[(size_t)r*3 + (t-25)];
  __syncthreads();

  // phase 1: frames for this residue's 192 points (48 qp, 48 kp, 96 vp)
  if (t < 192) {
    float* base; int pidx; float* sdst;
    if      (t <  48) { base = ws + OFF_LQ  + (size_t)r*HPQ3; pidx = t;    sdst = sLQ; }
    else if (t <  96) { base = ws + OFF_LK  + (size_t)r*HPQ3; pidx = t-48; sdst = sLK; }
    else              { base = ws + OFF_LVP + (size_t)r*HPV3; pidx = t-96; sdst = 0;   }
    float x = base[pidx*3+0], y = base[pidx*3+1], z = base[pidx*3+2];
    float o0 = sR[0]*x + sR[1]*y + sR[2]*z + sT[0];
    float o1 = sR[3]*x + sR[4]*y + sR[5]*z + sT[1];
    float o2 = sR[6]*x + sR[7]*y + sR[8]*z + sT[2];
    base[pidx*3+0]=o0; base[pidx*3+1]=o1; base[pidx*3+2]=o2;
    if (sdst) { sdst[pidx*3+0]=o0; sdst[pidx*3+1]=o1; sdst[pidx*3+2]=o2; }
  }
  __syncthreads();

  // phase 2: khat/qhat rows (k/q from global, lk/lq from LDS)
  for (int i = t; i < NH*32; i += 256) {
    const int h = i >> 5, j = i & 31;
    const float* kk = ws + OFF_K + (size_t)r*HC + h*CC;
    const float* qq = ws + OFF_Q + (size_t)r*HC + h*CC;
    const float* lk = sLK + h*12;
    const float* lq = sLQ + h*12;
    float kv, qv;
    if (j < 16)      { kv = kk[j];    qv = SCALE_SINGLE * qq[j]; }
    else if (j < 28) { kv = lk[j-16]; qv = -2.f*SCALE_FRAME*sSp[h]*lq[j-16]; }
    else if (j == 28) {
      float s2 = 0.f;
      #pragma unroll
      for (int e=0;e<12;e++) { float v = lk[e]; s2 += v*v; }
      kv = SCALE_FRAME * sSp[h] * s2;
      qv = 1.f;
    } else { kv = 0.f; qv = 0.f; }
    ws[OFF_KH + ((size_t)h*NRES + r)*32 + j] = kv;
    ws[OFF_QH + ((size_t)h*NRES + r)*32 + j] = qv;
  }
}

// ---------------------------------------------------------------------------
// Kernel 1d: batched GEMM  wlog[n][h][m] = qhat_h[n,:] . khat_h[m,:]
// ---------------------------------------------------------------------------
#define QK_P 68
__global__ __launch_bounds__(256) void k_qk(float* __restrict__ ws)
{
  __shared__ __align__(16) float Qs[32*QK_P];   // 8704 B
  __shared__ __align__(16) float Ks[32*QK_P];   // 8704 B

  const int bid = blockIdx.x;
  const int h  = bid >> 6;
  const int nt = (bid >> 3) & 7;
  const int mt = bid & 7;
  const int t  = threadIdx.x;
  const int tc = t & 15, tr = t >> 4;

  const float4* qsrc = (const float4*)(ws + OFF_QH + ((size_t)h*NRES + nt*64)*32);
  const float4* ksrc = (const float4*)(ws + OFF_KH + ((size_t)h*NRES + mt*64)*32);

  #pragma unroll
  for (int u = 0; u < 2; ++u) {
    int idx = t + u*256;            // 0..511
    int r = idx >> 3, j4 = idx & 7;
    float4 qv = qsrc[idx];
    float4 kv = ksrc[idx];
    Qs[(j4*4+0)*QK_P + r] = qv.x;
    Qs[(j4*4+1)*QK_P + r] = qv.y;
    Qs[(j4*4+2)*QK_P + r] = qv.z;
    Qs[(j4*4+3)*QK_P + r] = qv.w;
    Ks[(j4*4+0)*QK_P + r] = kv.x;
    Ks[(j4*4+1)*QK_P + r] = kv.y;
    Ks[(j4*4+2)*QK_P + r] = kv.z;
    Ks[(j4*4+3)*QK_P + r] = kv.w;
  }
  __syncthreads();

  float acc[4][4];
  #pragma unroll
  for (int i=0;i<4;i++)
    #pragma unroll
    for (int k2=0;k2<4;k2++) acc[i][k2]=0.f;

  #pragma unroll
  for (int j = 0; j < 32; ++j) {
    float4 qv = *(const float4*)&Qs[j*QK_P + tr*4];
    float4 kv = *(const float4*)&Ks[j*QK_P + tc*4];
    acc[0][0] += qv.x*kv.x; acc[0][1] += qv.x*kv.y; acc[0][2] += qv.x*kv.z; acc[0][3] += qv.x*kv.w;
    acc[1][0] += qv.y*kv.x; acc[1][1] += qv.y*kv.y; acc[1][2] += qv.y*kv.z; acc[1][3] += qv.y*kv.w;
    acc[2][0] += qv.z*kv.x; acc[2][1] += qv.z*kv.y; acc[2][2] += qv.z*kv.z; acc[2][3] += qv.z*kv.w;
    acc[3][0] += qv.w*kv.x; acc[3][1] += qv.w*kv.y; acc[3][2] += qv.w*kv.z; acc[3][3] += qv.w*kv.w;
  }

  float* wlog = ws + OFF_LOG;
  #pragma unroll
  for (int i = 0; i < 4; ++i) {
    int n = nt*64 + tr*4 + i;
    *(float4*)&wlog[((size_t)n*NH + h)*NRES + mt*64 + tc*4] =
        make_float4(acc[i][0], acc[i][1], acc[i][2], acc[i][3]);
  }
}

// ---------------------------------------------------------------------------
// Kernel 2 (PRIMARY): fused attention. Phase A = round-10 measured-best;
// C1/C2 register-pipelined (round 14, neutral-to-positive).
// ---------------------------------------------------------------------------
__global__ __launch_bounds__(512) void k_attn2(
    const float* __restrict__ pair,
    const float* __restrict__ rot, const float* __restrict__ trans,
    const float* __restrict__ Wb,
    float* __restrict__ ws)
{
  const int n = blockIdx.x;
  const int t = threadIdx.x;

  __shared__ __align__(16) float sLogit[NH*LROW];   // 24768 B
  // union: phase A pair-stage [16][ZP] (33024 B) / phase C1 sOP[4][NH*CZ] (24576 B)
  __shared__ __align__(16) float sU[16*ZP];         // 33024 B
  __shared__ __align__(16) float sOL[HPV3];
  __shared__ float sR[9];
  __shared__ float sT[3];

  const float* v    = ws + OFF_V;
  const float* lvp  = ws + OFF_LVP;
  const float* wlog = ws + OFF_LOG;
  float* att = ws + OFF_ATT;

  if (t >= 488 && t < 497)      sR[t-488] = rot[(size_t)n*9 + (t-488)];
  else if (t >= 497 && t < 500) sT[t-497] = trans[(size_t)n*3 + (t-497)];

  // ---------------- Phase A: pipelined staged pair-bias + precomputed qk ---
  {
    float acch[NH];
    #pragma unroll
    for (int h=0;h<NH;h++)
      acch[h] = wlog[((size_t)n*NH + h)*NRES + t];   // coalesced qk term

    const float4* pr4 = (const float4*)(pair + (size_t)n*NRES*CZ);

    // prefetch chunk 0 into registers (addresses: idx = t + j*512)
    float4 c0 = pr4[(size_t)((t +    0) >> 2)*32 + 0*4 + (t & 3)];
    float4 c1 = pr4[(size_t)((t +  512) >> 2)*32 + 0*4 + (t & 3)];
    float4 c2 = pr4[(size_t)((t + 1024) >> 2)*32 + 0*4 + (t & 3)];
    float4 c3 = pr4[(size_t)((t + 1536) >> 2)*32 + 0*4 + (t & 3)];

    #pragma unroll 1
    for (int zc = 0; zc < 8; ++zc) {
      __syncthreads();                    // prev chunk's LDS reads done
      {
#define WR_J(CJ, J)                                                   \
        { int idx = t + (J)*512;                                      \
          int row = idx >> 2, q = idx & 3;                            \
          sU[(q*4+0)*ZP + row] = CJ.x;                                \
          sU[(q*4+1)*ZP + row] = CJ.y;                                \
          sU[(q*4+2)*ZP + row] = CJ.z;                                \
          sU[(q*4+3)*ZP + row] = CJ.w; }
        WR_J(c0, 0) WR_J(c1, 1) WR_J(c2, 2) WR_J(c3, 3)
#undef WR_J
      }
      if (zc < 7) {
        c0 = pr4[(size_t)((t +    0) >> 2)*32 + (zc+1)*4 + (t & 3)];
        c1 = pr4[(size_t)((t +  512) >> 2)*32 + (zc+1)*4 + (t & 3)];
        c2 = pr4[(size_t)((t + 1024) >> 2)*32 + (zc+1)*4 + (t & 3)];
        c3 = pr4[(size_t)((t + 1536) >> 2)*32 + (zc+1)*4 + (t & 3)];
      }
      __syncthreads();
      #pragma unroll
      for (int e = 0; e < 16; ++e) {
        float pv = sU[e*ZP + t];
        const float* wrow = Wb + (size_t)(zc*16 + e)*NH;
        #pragma unroll
        for (int h=0;h<NH;h++) acch[h] += pv * wrow[h];
      }
    }
    #pragma unroll
    for (int h=0;h<NH;h++) sLogit[h*LROW + t] = acch[h];
  }
  __syncthreads();

  // ---------------- Phase B: softmax over m, wave per head -----------------
  {
    int wave = t >> 6, lane = t & 63;
    for (int h = wave; h < NH; h += 8) {
      float x[8]; float mx = -1e30f;
      #pragma unroll
      for (int j=0;j<8;j++) { x[j] = sLogit[h*LROW + lane + j*64]; mx = fmaxf(mx, x[j]); }
      #pragma unroll
      for (int d=1; d<64; d<<=1) mx = fmaxf(mx, __shfl_xor(mx, d, 64));
      float s = 0.f;
      #pragma unroll
      for (int j=0;j<8;j++) { x[j] = __expf(x[j]-mx); s += x[j]; }
      #pragma unroll
      for (int d=1; d<64; d<<=1) s += __shfl_xor(s, d, 64);
      float inv = 1.f/s;
      #pragma unroll
      for (int j=0;j<8;j++) sLogit[h*LROW + lane + j*64] = x[j]*inv;
    }
  }
  __syncthreads();

  // ---------------- Phase C1: o_pair, register-pipelined -------------------
  {
    const int zq = t & 31;
    const int hg = (t >> 5) & 3;
    const int mg = t >> 7;
    float a0[4] = {0,0,0,0}, a1[4] = {0,0,0,0}, a2[4] = {0,0,0,0};
    const float* pb = pair + (size_t)n*NRES*CZ + zq*4;

    float4 pc0 = *(const float4*)(pb + (size_t)(mg*128 + 0)*CZ);
    float4 pc1 = *(const float4*)(pb + (size_t)(mg*128 + 1)*CZ);
    float4 pc2 = *(const float4*)(pb + (size_t)(mg*128 + 2)*CZ);
    float4 pc3 = *(const float4*)(pb + (size_t)(mg*128 + 3)*CZ);

#define C1_FMA(M0)                                                        \
    {                                                                     \
      float4 w0 = *(const float4*)&sLogit[(hg+0)*LROW + (M0)];            \
      float4 w1 = *(const float4*)&sLogit[(hg+4)*LROW + (M0)];            \
      float4 w2 = *(const float4*)&sLogit[(hg+8)*LROW + (M0)];            \
      const float* w0p = (const float*)&w0;                               \
      const float* w1p = (const float*)&w1;                               \
      const float* w2p = (const float*)&w2;                               \
      const float* q0 = (const float*)&pc0;                               \
      const float* q1 = (const float*)&pc1;                               \
      const float* q2 = (const float*)&pc2;                               \
      const float* q3 = (const float*)&pc3;                               \
      _Pragma("unroll")                                                   \
      for (int e=0;e<4;e++) {                                             \
        a0[e] += w0p[0]*q0[e] + w0p[1]*q1[e] + w0p[2]*q2[e] + w0p[3]*q3[e]; \
        a1[e] += w1p[0]*q0[e] + w1p[1]*q1[e] + w1p[2]*q2[e] + w1p[3]*q3[e]; \
        a2[e] += w2p[0]*q0[e] + w2p[1]*q1[e] + w2p[2]*q2[e] + w2p[3]*q3[e]; \
      }                                                                   \
    }

    for (int mb = 0; mb < 31; ++mb) {
      int m0 = mg*128 + mb*4;
      float4 pn0 = *(const float4*)(pb + (size_t)(m0+4)*CZ);
      float4 pn1 = *(const float4*)(pb + (size_t)(m0+5)*CZ);
      float4 pn2 = *(const float4*)(pb + (size_t)(m0+6)*CZ);
      float4 pn3 = *(const float4*)(pb + (size_t)(m0+7)*CZ);
      C1_FMA(m0)
      pc0 = pn0; pc1 = pn1; pc2 = pn2; pc3 = pn3;
    }
    C1_FMA(mg*128 + 31*4)
#undef C1_FMA

    *(float4*)&sU[mg*(NH*CZ) + (hg+0)*CZ + zq*4] = make_float4(a0[0],a0[1],a0[2],a0[3]);
    *(float4*)&sU[mg*(NH*CZ) + (hg+4)*CZ + zq*4] = make_float4(a1[0],a1[1],a1[2],a1[3]);
    *(float4*)&sU[mg*(NH*CZ) + (hg+8)*CZ + zq*4] = make_float4(a2[0],a2[1],a2[2],a2[3]);
  }

  // ---------------- Phase C2: o_single / o_local, register-pipelined -------
  {
    if (t < 480) {
      float acc = 0.f;
      const float* src; int stride; int off; int h;
      if (t < 192) { h = t >> 4;        src = v;   stride = HC;   off = t;      }
      else         { int idx = t - 192; h = idx/24; src = lvp; stride = HPV3; off = idx; }
      const float* wrow = sLogit + h*LROW;

      float s0 = src[(size_t)0*stride + off];
      float s1 = src[(size_t)1*stride + off];
      float s2 = src[(size_t)2*stride + off];
      float s3 = src[(size_t)3*stride + off];
      for (int m0 = 0; m0 < NRES-4; m0 += 4) {
        float n0 = src[(size_t)(m0+4)*stride + off];
        float n1 = src[(size_t)(m0+5)*stride + off];
        float n2 = src[(size_t)(m0+6)*stride + off];
        float n3 = src[(size_t)(m0+7)*stride + off];
        float4 w4 = *(const float4*)&wrow[m0];
        acc += w4.x*s0 + w4.y*s1 + w4.z*s2 + w4.w*s3;
        s0 = n0; s1 = n1; s2 = n2; s3 = n3;
      }
      {
        float4 w4 = *(const float4*)&wrow[NRES-4];
        acc += w4.x*s0 + w4.y*s1 + w4.z*s2 + w4.w*s3;
      }

      if (t < 192) {
        int h2 = t >> 4;
        att[(size_t)n*ATTD + h2*176 + (t & 15)] = acc;
      } else {
        sOL[t-192] = acc;
      }
    }
  }
  __syncthreads();

  for (int o = t; o < NH*CZ; o += 512) {
    float sres = sU[0*(NH*CZ) + o] + sU[1*(NH*CZ) + o]
               + sU[2*(NH*CZ) + o] + sU[3*(NH*CZ) + o];
    int h = o >> 7, z = o & 127;
    att[(size_t)n*ATTD + h*176 + 16 + z] = sres;
  }

  if (t < 96) {
    int h = t / 8, p = t % 8;
    float x = sOL[h*24 + p*3 + 0] - sT[0];
    float y = sOL[h*24 + p*3 + 1] - sT[1];
    float z = sOL[h*24 + p*3 + 2] - sT[2];
    float o0 = sR[0]*x + sR[3]*y + sR[6]*z;
    float o1 = sR[1]*x + sR[4]*y + sR[7]*z;
    float o2 = sR[2]*x + sR[5]*y + sR[8]*z;
    float nm = sqrtf(o0*o0 + o1*o1 + o2*o2);
    float* ab = att + (size_t)n*ATTD + h*176;
    ab[144 + p*3 + 0] = o0;
    ab[144 + p*3 + 1] = o1;
    ab[144 + p*3 + 2] = o2;
    ab[168 + p] = nm;
  }
}

// ---------------------------------------------------------------------------
// Kernel 2 (FALLBACK: round-0 fused path, used only if ws too small)
// ---------------------------------------------------------------------------
__global__ __launch_bounds__(512) void k_attn(
    const float* __restrict__ pair,
    const float* __restrict__ rot, const float* __restrict__ trans,
    const float* __restrict__ Wb, const float* __restrict__ scale_head,
    float* __restrict__ ws)
{
  const int n = blockIdx.x;
  const int t = threadIdx.x;

  __shared__ __align__(16) float sLogit[NH*LROW];
  __shared__ __align__(16) float sOP[4][NH*CZ];
  __shared__ __align__(16) float sQ[HC];
  __shared__ __align__(16) float sLQ[HPQ3];
  __shared__ float sSp[NH];
  __shared__ __align__(16) float sOL[HPV3];
  __shared__ float sR[9];
  __shared__ float sT[3];

  const float* q   = ws + OFF_Q;
  const float* k   = ws + OFF_K;
  const float* v   = ws + OFF_V;
  const float* lq  = ws + OFF_LQ;
  const float* lk  = ws + OFF_LK;
  const float* lvp = ws + OFF_LVP;
  float* att = ws + OFF_ATT;

  if (t < 192)               sQ[t]      = q[(size_t)n*HC + t];
  else if (t < 336)          sLQ[t-192] = lq[(size_t)n*HPQ3 + (t-192)];
  else if (t < 348) { float x = scale_head[t-336];
                      sSp[t-336] = (x > 20.f) ? x : log1pf(__expf(x)); }
  else if (t < 357)          sR[t-348]  = rot[(size_t)n*9 + (t-348)];
  else if (t < 360)          sT[t-357]  = trans[(size_t)n*3 + (t-357)];
  __syncthreads();

  {
    const int m = t;
    float acch[NH];
    #pragma unroll
    for (int h=0;h<NH;h++) acch[h]=0.f;

    const float4* pr = (const float4*)(pair + ((size_t)n*NRES + m)*CZ);
    for (int zq = 0; zq < CZ/4; ++zq) {
      float4 p4 = pr[zq];
      const float* pp = (const float*)&p4;
      #pragma unroll
      for (int e=0;e<4;e++) {
        float pv_ = pp[e];
        const float* wrow = Wb + (size_t)(zq*4+e)*NH;
        #pragma unroll
        for (int h=0;h<NH;h++) acch[h] += pv_ * wrow[h];
      }
    }

    #pragma unroll
    for (int h=0;h<NH;h++) {
      const float4* kr = (const float4*)(k + (size_t)m*HC + h*CC);
      const float* qrow = sQ + h*CC;
      float d = 0.f;
      #pragma unroll
      for (int j=0;j<4;j++) {
        float4 k4 = kr[j];
        d += k4.x*qrow[j*4+0] + k4.y*qrow[j*4+1] + k4.z*qrow[j*4+2] + k4.w*qrow[j*4+3];
      }
      acch[h] += SCALE_SINGLE * d;

      const float* lkr = lk + (size_t)m*HPQ3 + h*12;
      const float* lqr = sLQ + h*12;
      float d2 = 0.f;
      #pragma unroll
      for (int j=0;j<12;j++) { float df = lqr[j]-lkr[j]; d2 += df*df; }
      acch[h] += SCALE_FRAME * sSp[h] * d2;

      sLogit[h*LROW + m] = acch[h];
    }
  }
  __syncthreads();

  {
    int wave = t >> 6, lane = t & 63;
    for (int h = wave; h < NH; h += 8) {
      float x[8]; float mx = -1e30f;
      #pragma unroll
      for (int j=0;j<8;j++) { x[j] = sLogit[h*LROW + lane + j*64]; mx = fmaxf(mx, x[j]); }
      #pragma unroll
      for (int d=1; d<64; d<<=1) mx = fmaxf(mx, __shfl_xor(mx, d, 64));
      float s = 0.f;
      #pragma unroll
      for (int j=0;j<8;j++) { x[j] = __expf(x[j]-mx); s += x[j]; }
      #pragma unroll
      for (int d=1; d<64; d<<=1) s += __shfl_xor(s, d, 64);
      float inv = 1.f/s;
      #pragma unroll
      for (int j=0;j<8;j++) sLogit[h*LROW + lane + j*64] = x[j]*inv;
    }
  }
  __syncthreads();

  {
    const int zq = t & 31;
    const int hg = (t >> 5) & 3;
    const int mg = t >> 7;
    float a0[4] = {0,0,0,0}, a1[4] = {0,0,0,0}, a2[4] = {0,0,0,0};
    const float* pb = pair + (size_t)n*NRES*CZ + zq*4;
    for (int mb = 0; mb < 32; ++mb) {
      int m0 = mg*128 + mb*4;
      float4 w0 = *(const float4*)&sLogit[(hg+0)*LROW + m0];
      float4 w1 = *(const float4*)&sLogit[(hg+4)*LROW + m0];
      float4 w2 = *(const float4*)&sLogit[(hg+8)*LROW + m0];
      const float* w0p = (const float*)&w0;
      const float* w1p = (const float*)&w1;
      const float* w2p = (const float*)&w2;
      #pragma unroll
      for (int i=0;i<4;i++) {
        float4 p4 = *(const float4*)(pb + (size_t)(m0+i)*CZ);
        const float* pp = (const float*)&p4;
        float f0 = w0p[i], f1 = w1p[i], f2 = w2p[i];
        #pragma unroll
        for (int e=0;e<4;e++) {
          a0[e] += f0*pp[e]; a1[e] += f1*pp[e]; a2[e] += f2*pp[e];
        }
      }
    }
    *(float4*)&sOP[mg][(hg+0)*CZ + zq*4] = make_float4(a0[0],a0[1],a0[2],a0[3]);
    *(float4*)&sOP[mg][(hg+4)*CZ + zq*4] = make_float4(a1[0],a1[1],a1[2],a1[3]);
    *(float4*)&sOP[mg][(hg+8)*CZ + zq*4] = make_float4(a2[0],a2[1],a2[2],a2[3]);
  }

  {
    if (t < 480) {
      float acc = 0.f;
      const float* src; int stride; int off; int h;
      if (t < 192) { h = t >> 4;        src = v;   stride = HC;   off = t;      }
      else         { int idx = t - 192; h = idx/24; src = lvp; stride = HPV3; off = idx; }
      const float* wrow = sLogit + h*LROW;
      for (int m0 = 0; m0 < NRES; m0 += 4) {
        float4 w4 = *(const float4*)&wrow[m0];
        acc += w4.x * src[(size_t)(m0+0)*stride + off];
        acc += w4.y * src[(size_t)(m0+1)*stride + off];
        acc += w4.z * src[(size_t)(m0+2)*stride + off];
        acc += w4.w * src[(size_t)(m0+3)*stride + off];
      }
      if (t < 192) {
        int h2 = t >> 4;
        att[(size_t)n*ATTD + h2*176 + (t & 15)] = acc;
      } else {
        sOL[t-192] = acc;
      }
    }
  }
  __syncthreads();

  for (int o = t; o < NH*CZ; o += 512) {
    float sres = sOP[0][o] + sOP[1][o] + sOP[2][o] + sOP[3][o];
    int h = o >> 7, z = o & 127;
    att[(size_t)n*ATTD + h*176 + 16 + z] = sres;
  }

  if (t < 96) {
    int h = t / 8, p = t % 8;
    float x = sOL[h*24 + p*3 + 0] - sT[0];
    float y = sOL[h*24 + p*3 + 1] - sT[1];
    float z = sOL[h*24 + p*3 + 2] - sT[2];
    float o0 = sR[0]*x + sR[3]*y + sR[6]*z;
    float o1 = sR[1]*x + sR[4]*y + sR[7]*z;
    float o2 = sR[2]*x + sR[5]*y + sR[8]*z;
    float nm = sqrtf(o0*o0 + o1*o1 + o2*o2);
    float* ab = att + (size_t)n*ATTD + h*176;
    ab[144 + p*3 + 0] = o0;
    ab[144 + p*3 + 1] = o1;
    ab[144 + p*3 + 2] = o2;
    ab[168 + p] = nm;
  }
}

// ---------------------------------------------------------------------------
// Kernel 3: out = att[512,2112] @ Wout[2112,384], K-split tiled GEMM.
// ---------------------------------------------------------------------------
#define KOUT_BK 24

__global__ __launch_bounds__(256) void k_out_part(
    const float* __restrict__ ws, const float* __restrict__ Wout,
    float* __restrict__ part, int KS)
{
  const float* att = ws + OFF_ATT;
  const int bid  = blockIdx.x;
  const int ks   = bid / 48;
  const int tile = bid % 48;
  const int rb   = tile / 6, cb = tile % 6;
  const int KLEN = ATTD / KS;
  const int k0b  = ks * KLEN;

  __shared__ __align__(16) float A_s[64][KOUT_BK+1];
  __shared__ __align__(16) float B_s[KOUT_BK][64];

  const int t  = threadIdx.x;
  const int tc = t & 15, tr = t >> 4;

  float acc[4][4];
  #pragma unroll
  for (int i=0;i<4;i++)
    #pragma unroll
    for (int j=0;j<4;j++) acc[i][j]=0.f;

  for (int k0 = k0b; k0 < k0b + KLEN; k0 += KOUT_BK) {
    __syncthreads();
    #pragma unroll
    for (int j = 0; j < 6; ++j) {
      int idx = t + j*256;
      int r  = idx / KOUT_BK, kk = idx % KOUT_BK;
      A_s[r][kk] = att[(size_t)(rb*64 + r)*ATTD + k0 + kk];
      int kk2 = idx >> 6, c = idx & 63;
      B_s[kk2][c] = Wout[(size_t)(k0 + kk2)*CSZ + cb*64 + c];
    }
    __syncthreads();
    #pragma unroll
    for (int kk = 0; kk < KOUT_BK; ++kk) {
      float4 b4 = *(const float4*)&B_s[kk][tc*4];
      float a0 = A_s[tr*4+0][kk];
      float a1 = A_s[tr*4+1][kk];
      float a2 = A_s[tr*4+2][kk];
      float a3 = A_s[tr*4+3][kk];
      acc[0][0] += a0*b4.x; acc[0][1] += a0*b4.y; acc[0][2] += a0*b4.z; acc[0][3] += a0*b4.w;
      acc[1][0] += a1*b4.x; acc[1][1] += a1*b4.y; acc[1][2] += a1*b4.z; acc[1][3] += a1*b4.w;
      acc[2][0] += a2*b4.x; acc[2][1] += a2*b4.y; acc[2][2] += a2*b4.z; acc[2][3] += a2*b4.w;
      acc[3][0] += a3*b4.x; acc[3][1] += a3*b4.y; acc[3][2] += a3*b4.z; acc[3][3] += a3*b4.w;
    }
  }

  float* pb = part + (size_t)ks*NRES*CSZ;
  #pragma unroll
  for (int i=0;i<4;i++) {
    int row = rb*64 + tr*4 + i;
    int col = cb*64 + tc*4;
    *(float4*)&pb[(size_t)row*CSZ + col] =
        make_float4(acc[i][0], acc[i][1], acc[i][2], acc[i][3]);
  }
}

__global__ __launch_bounds__(256) void k_out_reduce(
    const float* __restrict__ part, const float* __restrict__ bout,
    float* __restrict__ out, int KS)
{
  int idx4 = blockIdx.x*256 + threadIdx.x;
  if (idx4 >= NRES*CSZ/4) return;
  int c4 = idx4 % (CSZ/4);
  float4 s = ((const float4*)bout)[c4];
  const float4* p4 = (const float4*)part;
  for (int ks = 0; ks < KS; ++ks) {
    float4 v = p4[(size_t)ks*(NRES*CSZ/4) + idx4];
    s.x += v.x; s.y += v.y; s.z += v.z; s.w += v.w;
  }
  ((float4*)out)[idx4] = s;
}

__global__ __launch_bounds__(256) void k_out_v1(
    const float* __restrict__ ws, const float* __restrict__ Wout,
    const float* __restrict__ bout, float* __restrict__ out)
{
  const float* att = ws + OFF_ATT;
  int cb = blockIdx.x % 6;
  int rb = blockIdx.x / 6;
  int t  = threadIdx.x;
  int c  = cb*64 + (t & 63);
  int rg = t >> 6;
  int r0 = rb*16;
  float acc[4] = {0.f,0.f,0.f,0.f};
  for (int a = 0; a < ATTD; ++a) {
    float wv = Wout[(size_t)a*CSZ + c];
    #pragma unroll
    for (int i=0;i<4;i++)
      acc[i] += att[(size_t)(r0 + rg + 4*i)*ATTD + a] * wv;
  }
  float b = bout[c];
  #pragma unroll
  for (int i=0;i<4;i++)
    out[(size_t)(r0 + rg + 4*i)*CSZ + c] = acc[i] + b;
}

// ---------------------------------------------------------------------------
extern "C" void kernel_launch(void* const* d_in, const int* in_sizes, int n_in,
                              void* d_out, int out_size, void* d_ws, size_t ws_size,
                              hipStream_t stream) {
  const float* S     = (const float*)d_in[0];
  const float* pair  = (const float*)d_in[1];
  const float* rot   = (const float*)d_in[2];
  const float* trans = (const float*)d_in[3];
  const float* Wq    = (const float*)d_in[4];
  const float* Wk    = (const float*)d_in[5];
  const float* Wv    = (const float*)d_in[6];
  const float* Wqp   = (const float*)d_in[7];
  const float* Wkp   = (const float*)d_in[8];
  const float* Wvp   = (const float*)d_in[9];
  const float* Wb    = (const float*)d_in[10];
  const float* Wout  = (const float*)d_in[11];
  const float* bout  = (const float*)d_in[12];
  const float* sh    = (const float*)d_in[13];
  float* out = (float*)d_out;
  float* ws  = (float*)d_ws;

  hipLaunchKernelGGL(k_proj2,  dim3(16*18), dim3(256), 0, stream,
                     S, Wq, Wk, Wv, Wqp, Wkp, Wvp, ws);
  hipLaunchKernelGGL(k_frames_hat, dim3(NRES), dim3(256), 0, stream,
                     rot, trans, sh, ws);

  const size_t need_new = (size_t)(OFF_LOG + LOG_FLOATS) * sizeof(float);
  if (ws_size >= need_new) {
    hipLaunchKernelGGL(k_qk,    dim3(NH*64), dim3(256), 0, stream, ws);
    hipLaunchKernelGGL(k_attn2, dim3(NRES), dim3(512), 0, stream,
                       pair, rot, trans, Wb, ws);
  } else {
    hipLaunchKernelGGL(k_attn,  dim3(NRES), dim3(512), 0, stream,
                       pair, rot, trans, Wb, sh, ws);
  }

  int KS = 0;
  const int cands[4] = {8, 4, 2, 1};
  for (int i = 0; i < 4; ++i) {
    size_t need = ((size_t)OFF_PART + (size_t)cands[i]*NRES*CSZ) * sizeof(float);
    if (need <= ws_size) { KS = cands[i]; break; }
  }
  if (KS > 0) {
    hipLaunchKernelGGL(k_out_part, dim3(48*KS), dim3(256), 0, stream,
                       ws, Wout, ws + OFF_PART, KS);
    hipLaunchKernelGGL(k_out_reduce, dim3((NRES*CSZ/4 + 255)/256), dim3(256), 0, stream,
                       ws + OFF_PART, bout, out, KS);
  } else {
    hipLaunchKernelGGL(k_out_v1, dim3(32*6), dim3(256), 0, stream,
                       ws, Wout, bout, out);
  }
}